// Round 5
// baseline (803.188 us; speedup 1.0000x reference)
//
#include <hip/hip_runtime.h>
#include <hip/hip_bf16.h>

#define N_NODES_C 50000
#define N_EDGES_C 800000
// Main edge launch covers rows [0, EDGE_MAIN_ROWS); tail uses the fp32 path
// so the bf16 scratch parked at the end of the edge-output region is dead
// before the tail launch overwrites it.
#define EDGE_MAIN_ROWS 774144            // 6048 * 128
#define EDGE_TAIL_BLOCKS 202             // (800000-774144)/128

typedef __attribute__((ext_vector_type(8))) short bf16x8;
typedef __attribute__((ext_vector_type(4))) float f32x4;

__device__ __forceinline__ unsigned short f2bf(float f) {
    unsigned int x = __float_as_uint(f);
    unsigned int r = x + 0x7fffu + ((x >> 16) & 1u);   // RNE
    return (unsigned short)(r >> 16);
}

// ---------------------------------------------------------------------------
// CSR build: count -> scan -> fill
// ---------------------------------------------------------------------------
__global__ __launch_bounds__(256) void count_k(const int* __restrict__ v, int* __restrict__ cnt)
{
    int e = blockIdx.x * 256 + threadIdx.x;
    atomicAdd(&cnt[v[e]], 1);
}

__global__ __launch_bounds__(1024) void scan_k(const int* __restrict__ cnt,
                                               int* __restrict__ rowst,
                                               int* __restrict__ cursor)
{
    __shared__ int wsum[16];
    int tid = threadIdx.x, lane = tid & 63, wid = tid >> 6;
    int carry = 0;
    for (int base = 0; base < N_NODES_C; base += 1024) {
        int i = base + tid;
        int x = (i < N_NODES_C) ? cnt[i] : 0;
        int s = x;
#pragma unroll
        for (int d = 1; d < 64; d <<= 1) {
            int t = __shfl_up(s, d, 64);
            if (lane >= d) s += t;
        }
        if (lane == 63) wsum[wid] = s;
        __syncthreads();
        if (wid == 0) {
            int w = (lane < 16) ? wsum[lane] : 0;
#pragma unroll
            for (int d = 1; d < 16; d <<= 1) {
                int t = __shfl_up(w, d, 64);
                if (lane >= d) w += t;
            }
            if (lane < 16) wsum[lane] = w;
        }
        __syncthreads();
        int offset = carry + (wid > 0 ? wsum[wid - 1] : 0);
        int excl = offset + s - x;
        if (i < N_NODES_C) { rowst[i] = excl; cursor[i] = excl; }
        carry += wsum[15];
        __syncthreads();
    }
    if (tid == 0) rowst[N_NODES_C] = carry;
}

__global__ __launch_bounds__(256) void fill_k(const int* __restrict__ v,
                                              const int* __restrict__ u,
                                              int* __restrict__ cursor,
                                              int2* __restrict__ pairs)
{
    int e = blockIdx.x * 256 + threadIdx.x;
    int pos = atomicAdd(&cursor[v[e]], 1);
    pairs[pos] = make_int2(e, u[e]);
}

// ---------------------------------------------------------------------------
// Aggregate: one block per dst node; 4 edge-groups of 64 lanes, float4/lane.
// ---------------------------------------------------------------------------
__global__ __launch_bounds__(256) void aggregate_k(
    const int2* __restrict__ pairs, const int* __restrict__ rowst,
    const float* __restrict__ nfeats, const float* __restrict__ efeats,
    float* __restrict__ h_neigh)
{
    __shared__ float4 red[256];
    int n = blockIdx.x, tid = threadIdx.x;
    int grp = tid >> 6, lane = tid & 63;
    int s = rowst[n], e_end = rowst[n + 1];
    int deg = e_end - s;

    float4 acc = make_float4(0.f, 0.f, 0.f, 0.f);
    for (int i = s + grp; i < e_end; i += 4) {
        int2 p = pairs[i];
        const float* src = (lane < 32)
            ? (nfeats + (size_t)p.y * 128 + lane * 4)
            : (efeats + (size_t)p.x * 128 + (lane - 32) * 4);
        float4 vv = *reinterpret_cast<const float4*>(src);
        acc.x += vv.x; acc.y += vv.y; acc.z += vv.z; acc.w += vv.w;
    }
    red[tid] = acc;
    __syncthreads();
    if (grp == 0) {
        float4 a = red[lane], b = red[64 + lane], c = red[128 + lane], d = red[192 + lane];
        float r = (deg > 0) ? 1.f / (float)deg : 0.f;
        float4 o;
        o.x = (a.x + b.x + c.x + d.x) * r;
        o.y = (a.y + b.y + c.y + d.y) * r;
        o.z = (a.z + b.z + c.z + d.z) * r;
        o.w = (a.w + b.w + c.w + d.w) * r;
        *reinterpret_cast<float4*>(h_neigh + (size_t)n * 256 + lane * 4) = o;
    }
}

// ---------------------------------------------------------------------------
// bf16-MFMA tile machinery. LDS [128 rows][64 k] bf16, swizzle
// byte ^= (row&7)<<4. stage_half_row: fp32 source (converts); used by
// node_k and the edge tail kernel.
// ---------------------------------------------------------------------------
__device__ __forceinline__ void stage_half_row(
    const float* __restrict__ src, char* __restrict__ lds, int row, int halfg)
{
#pragma unroll
    for (int g = 0; g < 4; ++g) {
        float4 f0 = reinterpret_cast<const float4*>(src)[g * 2 + 0];
        float4 f1 = reinterpret_cast<const float4*>(src)[g * 2 + 1];
        union { unsigned short s[8]; uint4 q; } pk;
        pk.s[0] = f2bf(f0.x); pk.s[1] = f2bf(f0.y);
        pk.s[2] = f2bf(f0.z); pk.s[3] = f2bf(f0.w);
        pk.s[4] = f2bf(f1.x); pk.s[5] = f2bf(f1.y);
        pk.s[6] = f2bf(f1.z); pk.s[7] = f2bf(f1.w);
        int byteoff = ((halfg * 4 + g) * 16) ^ ((row & 7) << 4);
        *reinterpret_cast<uint4*>(lds + row * 128 + byteoff) = pk.q;
    }
}

// MFMA on one staged k-slab (64 k): 2 chunks x 16 mfma, acc[4][4].
__device__ __forceinline__ void mfma_slab(
    const char* __restrict__ Xs, const char* __restrict__ Ws,
    int wm, int wn, int lane, f32x4 (&acc)[4][4])
{
#pragma unroll
    for (int c = 0; c < 2; ++c) {
        int kb = c * 64 + (lane >> 4) * 16;
        bf16x8 a[4], b[4];
#pragma unroll
        for (int i = 0; i < 4; ++i) {
            int row = wm * 64 + i * 16 + (lane & 15);
            a[i] = *reinterpret_cast<const bf16x8*>(
                Xs + row * 128 + (kb ^ ((row & 7) << 4)));
        }
#pragma unroll
        for (int j = 0; j < 4; ++j) {
            int row = wn * 64 + j * 16 + (lane & 15);
            b[j] = *reinterpret_cast<const bf16x8*>(
                Ws + row * 128 + (kb ^ ((row & 7) << 4)));
        }
#pragma unroll
        for (int i = 0; i < 4; ++i)
#pragma unroll
            for (int j = 0; j < 4; ++j)
                acc[i][j] = __builtin_amdgcn_mfma_f32_16x16x32_bf16(
                    a[i], b[j], acc[i][j], 0, 0, 0);
    }
}

__device__ __forceinline__ void epilogue_store(
    const f32x4 (&acc)[4][4], const float* __restrict__ bias,
    float* __restrict__ out, int row_base, int row_limit, int wm, int wn, int lane)
{
    int col0 = wn * 64 + (lane & 15);
    int row0 = row_base + wm * 64 + (lane >> 4) * 4;
#pragma unroll
    for (int j = 0; j < 4; ++j) {
        float bj = bias[col0 + j * 16];
#pragma unroll
        for (int i = 0; i < 4; ++i) {
#pragma unroll
            for (int r = 0; r < 4; ++r) {
                int row = row0 + i * 16 + r;
                if (row < row_limit) {
                    float val = fmaxf(acc[i][j][r] + bj, 0.f);
                    out[(size_t)row * 128 + col0 + j * 16] = val;
                }
            }
        }
    }
}

// ---------------------------------------------------------------------------
// K2: node update via bf16 MFMA; dual-writes h fp32 (output 0) + bf16 copy.
// ---------------------------------------------------------------------------
__global__ __launch_bounds__(256) void node_k(
    const float* __restrict__ nfeats, const float* __restrict__ h_neigh,
    const float* __restrict__ W, const float* __restrict__ bias,
    float* __restrict__ out, unsigned short* __restrict__ hb)
{
    __shared__ uint4 XsBuf[1024];
    __shared__ uint4 WsBuf[1024];
    char* Xs = (char*)XsBuf;
    char* Ws = (char*)WsBuf;

    int tid = threadIdx.x;
    int n0  = blockIdx.x * 128;
    int wave = tid >> 6, lane = tid & 63;
    int wm = wave >> 1, wn = wave & 1;
    int srow = tid >> 1, shalf = tid & 1;

    int nrow = n0 + srow;
    if (nrow >= N_NODES_C) nrow = N_NODES_C - 1;

    f32x4 acc[4][4];
#pragma unroll
    for (int i = 0; i < 4; ++i)
#pragma unroll
        for (int j = 0; j < 4; ++j) acc[i][j] = (f32x4)0.f;

#pragma unroll
    for (int k0 = 0; k0 < 384; k0 += 64) {
        const float* xsrc = (k0 < 128)
            ? (nfeats  + (size_t)nrow * 128 + k0         + shalf * 32)
            : (h_neigh + (size_t)nrow * 256 + (k0 - 128) + shalf * 32);
        stage_half_row(xsrc, Xs, srow, shalf);
        const float* wsrc = W + (size_t)srow * 384 + k0 + shalf * 32;
        stage_half_row(wsrc, Ws, srow, shalf);
        __syncthreads();
        mfma_slab(Xs, Ws, wm, wn, lane, acc);
        __syncthreads();
    }

    int col0 = wn * 64 + (lane & 15);
    int row0 = n0 + wm * 64 + (lane >> 4) * 4;
#pragma unroll
    for (int j = 0; j < 4; ++j) {
        float bj = bias[col0 + j * 16];
#pragma unroll
        for (int i = 0; i < 4; ++i) {
#pragma unroll
            for (int r = 0; r < 4; ++r) {
                int row = row0 + i * 16 + r;
                if (row < N_NODES_C) {
                    float val = fmaxf(acc[i][j][r] + bj, 0.f);
                    out[(size_t)row * 128 + col0 + j * 16] = val;
                    hb[(size_t)row * 128 + col0 + j * 16] = f2bf(val);
                }
            }
        }
    }
}

// ---------------------------------------------------------------------------
// W_edge fp32 -> bf16 (one-time prep).
// ---------------------------------------------------------------------------
__global__ __launch_bounds__(256) void prep_w_k(const float* __restrict__ W,
                                                unsigned short* __restrict__ wb)
{
    int i = blockIdx.x * 256 + threadIdx.x;   // grid = 32768/256
    wb[i] = f2bf(W[i]);
}

// ---------------------------------------------------------------------------
// K3 main: edge update from pre-converted bf16 h/W; register-prefetch
// staging (slab s+1 loads issued before MFMA of slab s).
// ---------------------------------------------------------------------------
__global__ __launch_bounds__(256) void edge_main_k(
    const unsigned short* __restrict__ hb, const int* __restrict__ u,
    const int* __restrict__ v, const unsigned short* __restrict__ wb,
    const float* __restrict__ bias, float* __restrict__ out)
{
    __shared__ uint4 XsBuf[1024];
    __shared__ uint4 WsBuf[1024];
    __shared__ int us[128], vs[128];
    char* Xs = (char*)XsBuf;
    char* Ws = (char*)WsBuf;

    int tid = threadIdx.x;
    int e0  = blockIdx.x * 128;
    if (tid < 128) us[tid]       = u[e0 + tid];
    else           vs[tid - 128] = v[e0 + tid - 128];
    __syncthreads();

    int wave = tid >> 6, lane = tid & 63;
    int wm = wave >> 1, wn = wave & 1;
    int srow = tid >> 1, shalf = tid & 1;

    f32x4 acc[4][4];
#pragma unroll
    for (int i = 0; i < 4; ++i)
#pragma unroll
        for (int j = 0; j < 4; ++j) acc[i][j] = (f32x4)0.f;

    uint4 xr[4], wr[4];
    {
        int node = us[srow];
        const uint4* xs = reinterpret_cast<const uint4*>(hb + (size_t)node * 128 + shalf * 32);
        const uint4* ws = reinterpret_cast<const uint4*>(wb + (size_t)srow * 256 + shalf * 32);
#pragma unroll
        for (int g = 0; g < 4; ++g) { xr[g] = xs[g]; wr[g] = ws[g]; }
    }

#pragma unroll
    for (int s = 0; s < 4; ++s) {
        if (s) __syncthreads();              // prev MFMA done reading LDS
#pragma unroll
        for (int g = 0; g < 4; ++g) {
            int bo = ((shalf * 4 + g) * 16) ^ ((srow & 7) << 4);
            *reinterpret_cast<uint4*>(Xs + srow * 128 + bo) = xr[g];
            *reinterpret_cast<uint4*>(Ws + srow * 128 + bo) = wr[g];
        }
        __syncthreads();
        if (s < 3) {                         // prefetch next slab during MFMA
            int k0 = (s + 1) * 64;
            int node = (k0 < 128) ? us[srow] : vs[srow];
            const uint4* xs = reinterpret_cast<const uint4*>(
                hb + (size_t)node * 128 + (k0 & 127) + shalf * 32);
            const uint4* ws = reinterpret_cast<const uint4*>(
                wb + (size_t)srow * 256 + k0 + shalf * 32);
#pragma unroll
            for (int g = 0; g < 4; ++g) { xr[g] = xs[g]; wr[g] = ws[g]; }
        }
        mfma_slab(Xs, Ws, wm, wn, lane, acc);
    }

    epilogue_store(acc, bias, out, e0, N_EDGES_C, wm, wn, lane);
}

// ---------------------------------------------------------------------------
// K3 tail: fp32-path edge kernel (identical math to R3) for the rows whose
// output region holds the bf16 scratch.
// ---------------------------------------------------------------------------
__global__ __launch_bounds__(256) void edge_tail_k(
    const float* __restrict__ h, const int* __restrict__ u,
    const int* __restrict__ v, const float* __restrict__ W,
    const float* __restrict__ bias, float* __restrict__ out)
{
    __shared__ uint4 XsBuf[1024];
    __shared__ uint4 WsBuf[1024];
    __shared__ int us[128], vs[128];
    char* Xs = (char*)XsBuf;
    char* Ws = (char*)WsBuf;

    int tid = threadIdx.x;
    int e0  = EDGE_MAIN_ROWS + blockIdx.x * 128;
    if (tid < 128) us[tid]       = u[e0 + tid];
    else           vs[tid - 128] = v[e0 + tid - 128];
    __syncthreads();

    int wave = tid >> 6, lane = tid & 63;
    int wm = wave >> 1, wn = wave & 1;
    int srow = tid >> 1, shalf = tid & 1;

    f32x4 acc[4][4];
#pragma unroll
    for (int i = 0; i < 4; ++i)
#pragma unroll
        for (int j = 0; j < 4; ++j) acc[i][j] = (f32x4)0.f;

#pragma unroll
    for (int k0 = 0; k0 < 256; k0 += 64) {
        int node = (k0 < 128) ? us[srow] : vs[srow];
        const float* xsrc = h + (size_t)node * 128 + (k0 & 127) + shalf * 32;
        stage_half_row(xsrc, Xs, srow, shalf);
        const float* wsrc = W + (size_t)srow * 256 + k0 + shalf * 32;
        stage_half_row(wsrc, Ws, srow, shalf);
        __syncthreads();
        mfma_slab(Xs, Ws, wm, wn, lane, acc);
        __syncthreads();
    }

    epilogue_store(acc, bias, out, e0, N_EDGES_C, wm, wn, lane);
}

// ---------------------------------------------------------------------------
extern "C" void kernel_launch(void* const* d_in, const int* in_sizes, int n_in,
                              void* d_out, int out_size, void* d_ws, size_t ws_size,
                              hipStream_t stream)
{
    const float* nfeats    = (const float*)d_in[0];
    const float* efeats    = (const float*)d_in[1];
    const int*   u         = (const int*)d_in[2];
    const int*   v         = (const int*)d_in[3];
    const float* W_apply_w = (const float*)d_in[4];
    const float* W_apply_b = (const float*)d_in[5];
    const float* W_edge_w  = (const float*)d_in[6];
    const float* W_edge_b  = (const float*)d_in[7];

    float* out      = (float*)d_out;
    float* h_nodes  = out;                                // [50000][128]
    float* edge_out = out + (size_t)N_NODES_C * 128;      // [800000][128]

    // --- Scratch overlays (all inside the 409.6 MB edge-output region) ---
    // Head: CSR + h_neigh, consumed before any edge kernel writes.
    float* scratch = edge_out;
    float* h_neigh = scratch;                              // 12.8M floats
    int*   cnt     = (int*)(scratch + 12800000);           // 50000
    int*   rowst   = cnt + N_NODES_C;                      // 50001
    int*   cursor  = rowst + N_NODES_C + 1;                // 50000
    int2*  pairs   = (int2*)(cursor + N_NODES_C + 2);      // 800000 int2
    // Tail: bf16 h (6.4M ushort) + bf16 W_edge (32768 ushort), read only by
    // edge_main_k (rows < EDGE_MAIN_ROWS); overwritten by edge_tail_k last.
    unsigned short* hb = (unsigned short*)(edge_out + (size_t)EDGE_MAIN_ROWS * 128);
    unsigned short* wb = hb + (size_t)N_NODES_C * 128;

    hipMemsetAsync(cnt, 0, N_NODES_C * sizeof(int), stream);

    count_k<<<N_EDGES_C / 256, 256, 0, stream>>>(v, cnt);
    scan_k<<<1, 1024, 0, stream>>>(cnt, rowst, cursor);
    fill_k<<<N_EDGES_C / 256, 256, 0, stream>>>(v, u, cursor, pairs);
    aggregate_k<<<N_NODES_C, 256, 0, stream>>>(pairs, rowst, nfeats, efeats, h_neigh);

    node_k<<<(N_NODES_C + 127) / 128, 256, 0, stream>>>(
        nfeats, h_neigh, W_apply_w, W_apply_b, h_nodes, hb);

    prep_w_k<<<32768 / 256, 256, 0, stream>>>(W_edge_w, wb);

    edge_main_k<<<EDGE_MAIN_ROWS / 128, 256, 0, stream>>>(
        hb, u, v, wb, W_edge_b, edge_out);

    edge_tail_k<<<EDGE_TAIL_BLOCKS, 256, 0, stream>>>(
        h_nodes, u, v, W_edge_w, W_edge_b, edge_out);
}

// Round 6
// 565.107 us; speedup vs baseline: 1.4213x; 1.4213x over previous
//
#include <hip/hip_runtime.h>
#include <hip/hip_bf16.h>

#define N_NODES_C 50000
#define N_EDGES_C 800000
// P (bf16 [50000][256]) overlays edge-output rows [0, 50000). edge_add_k
// writes rows [EDGE_HEAD_ROWS, 800000); edge_head_k (direct GEMM) computes
// rows [0, EDGE_HEAD_ROWS) last, after P is dead.
#define EDGE_HEAD_ROWS 50048             // 391 * 128
#define EDGE_ADD_BLOCKS 93744            // (800000-50048)*32/256

typedef __attribute__((ext_vector_type(8))) short bf16x8;
typedef __attribute__((ext_vector_type(4))) float f32x4;

__device__ __forceinline__ unsigned short f2bf(float f) {
    unsigned int x = __float_as_uint(f);
    unsigned int r = x + 0x7fffu + ((x >> 16) & 1u);   // RNE
    return (unsigned short)(r >> 16);
}
__device__ __forceinline__ float bf2f(unsigned short s) {
    return __uint_as_float(((unsigned int)s) << 16);
}

// ---------------------------------------------------------------------------
// CSR build: count -> scan -> fill
// ---------------------------------------------------------------------------
__global__ __launch_bounds__(256) void count_k(const int* __restrict__ v, int* __restrict__ cnt)
{
    int e = blockIdx.x * 256 + threadIdx.x;
    atomicAdd(&cnt[v[e]], 1);
}

__global__ __launch_bounds__(1024) void scan_k(const int* __restrict__ cnt,
                                               int* __restrict__ rowst,
                                               int* __restrict__ cursor)
{
    __shared__ int wsum[16];
    int tid = threadIdx.x, lane = tid & 63, wid = tid >> 6;
    int carry = 0;
    for (int base = 0; base < N_NODES_C; base += 1024) {
        int i = base + tid;
        int x = (i < N_NODES_C) ? cnt[i] : 0;
        int s = x;
#pragma unroll
        for (int d = 1; d < 64; d <<= 1) {
            int t = __shfl_up(s, d, 64);
            if (lane >= d) s += t;
        }
        if (lane == 63) wsum[wid] = s;
        __syncthreads();
        if (wid == 0) {
            int w = (lane < 16) ? wsum[lane] : 0;
#pragma unroll
            for (int d = 1; d < 16; d <<= 1) {
                int t = __shfl_up(w, d, 64);
                if (lane >= d) w += t;
            }
            if (lane < 16) wsum[lane] = w;
        }
        __syncthreads();
        int offset = carry + (wid > 0 ? wsum[wid - 1] : 0);
        int excl = offset + s - x;
        if (i < N_NODES_C) { rowst[i] = excl; cursor[i] = excl; }
        carry += wsum[15];
        __syncthreads();
    }
    if (tid == 0) rowst[N_NODES_C] = carry;
}

__global__ __launch_bounds__(256) void fill_k(const int* __restrict__ v,
                                              const int* __restrict__ u,
                                              int* __restrict__ cursor,
                                              int2* __restrict__ pairs)
{
    int e = blockIdx.x * 256 + threadIdx.x;
    int pos = atomicAdd(&cursor[v[e]], 1);
    pairs[pos] = make_int2(e, u[e]);
}

// ---------------------------------------------------------------------------
// Aggregate: one block per dst node; 4 edge-groups of 64 lanes, float4/lane.
// ---------------------------------------------------------------------------
__global__ __launch_bounds__(256) void aggregate_k(
    const int2* __restrict__ pairs, const int* __restrict__ rowst,
    const float* __restrict__ nfeats, const float* __restrict__ efeats,
    float* __restrict__ h_neigh)
{
    __shared__ float4 red[256];
    int n = blockIdx.x, tid = threadIdx.x;
    int grp = tid >> 6, lane = tid & 63;
    int s = rowst[n], e_end = rowst[n + 1];
    int deg = e_end - s;

    float4 acc = make_float4(0.f, 0.f, 0.f, 0.f);
    for (int i = s + grp; i < e_end; i += 4) {
        int2 p = pairs[i];
        const float* src = (lane < 32)
            ? (nfeats + (size_t)p.y * 128 + lane * 4)
            : (efeats + (size_t)p.x * 128 + (lane - 32) * 4);
        float4 vv = *reinterpret_cast<const float4*>(src);
        acc.x += vv.x; acc.y += vv.y; acc.z += vv.z; acc.w += vv.w;
    }
    red[tid] = acc;
    __syncthreads();
    if (grp == 0) {
        float4 a = red[lane], b = red[64 + lane], c = red[128 + lane], d = red[192 + lane];
        float r = (deg > 0) ? 1.f / (float)deg : 0.f;
        float4 o;
        o.x = (a.x + b.x + c.x + d.x) * r;
        o.y = (a.y + b.y + c.y + d.y) * r;
        o.z = (a.z + b.z + c.z + d.z) * r;
        o.w = (a.w + b.w + c.w + d.w) * r;
        *reinterpret_cast<float4*>(h_neigh + (size_t)n * 256 + lane * 4) = o;
    }
}

// ---------------------------------------------------------------------------
// bf16-MFMA tile machinery. LDS [128 rows][64 k] bf16, swizzle
// byte ^= (row&7)<<4.
// ---------------------------------------------------------------------------
__device__ __forceinline__ void stage_half_row(
    const float* __restrict__ src, char* __restrict__ lds, int row, int halfg)
{
#pragma unroll
    for (int g = 0; g < 4; ++g) {
        float4 f0 = reinterpret_cast<const float4*>(src)[g * 2 + 0];
        float4 f1 = reinterpret_cast<const float4*>(src)[g * 2 + 1];
        union { unsigned short s[8]; uint4 q; } pk;
        pk.s[0] = f2bf(f0.x); pk.s[1] = f2bf(f0.y);
        pk.s[2] = f2bf(f0.z); pk.s[3] = f2bf(f0.w);
        pk.s[4] = f2bf(f1.x); pk.s[5] = f2bf(f1.y);
        pk.s[6] = f2bf(f1.z); pk.s[7] = f2bf(f1.w);
        int byteoff = ((halfg * 4 + g) * 16) ^ ((row & 7) << 4);
        *reinterpret_cast<uint4*>(lds + row * 128 + byteoff) = pk.q;
    }
}

__device__ __forceinline__ void mfma_slab(
    const char* __restrict__ Xs, const char* __restrict__ Ws,
    int wm, int wn, int lane, f32x4 (&acc)[4][4])
{
#pragma unroll
    for (int c = 0; c < 2; ++c) {
        int kb = c * 64 + (lane >> 4) * 16;
        bf16x8 a[4], b[4];
#pragma unroll
        for (int i = 0; i < 4; ++i) {
            int row = wm * 64 + i * 16 + (lane & 15);
            a[i] = *reinterpret_cast<const bf16x8*>(
                Xs + row * 128 + (kb ^ ((row & 7) << 4)));
        }
#pragma unroll
        for (int j = 0; j < 4; ++j) {
            int row = wn * 64 + j * 16 + (lane & 15);
            b[j] = *reinterpret_cast<const bf16x8*>(
                Ws + row * 128 + (kb ^ ((row & 7) << 4)));
        }
#pragma unroll
        for (int i = 0; i < 4; ++i)
#pragma unroll
            for (int j = 0; j < 4; ++j)
                acc[i][j] = __builtin_amdgcn_mfma_f32_16x16x32_bf16(
                    a[i], b[j], acc[i][j], 0, 0, 0);
    }
}

__device__ __forceinline__ void epilogue_store(
    const f32x4 (&acc)[4][4], const float* __restrict__ bias,
    float* __restrict__ out, int row_base, int row_limit, int wm, int wn, int lane)
{
    int col0 = wn * 64 + (lane & 15);
    int row0 = row_base + wm * 64 + (lane >> 4) * 4;
#pragma unroll
    for (int j = 0; j < 4; ++j) {
        float bj = bias[col0 + j * 16];
#pragma unroll
        for (int i = 0; i < 4; ++i) {
#pragma unroll
            for (int r = 0; r < 4; ++r) {
                int row = row0 + i * 16 + r;
                if (row < row_limit) {
                    float val = fmaxf(acc[i][j][r] + bj, 0.f);
                    out[(size_t)row * 128 + col0 + j * 16] = val;
                }
            }
        }
    }
}

// ---------------------------------------------------------------------------
// K2: node update via bf16 MFMA. K=384, 6 slabs.
// ---------------------------------------------------------------------------
__global__ __launch_bounds__(256) void node_k(
    const float* __restrict__ nfeats, const float* __restrict__ h_neigh,
    const float* __restrict__ W, const float* __restrict__ bias,
    float* __restrict__ out)
{
    __shared__ uint4 XsBuf[1024];
    __shared__ uint4 WsBuf[1024];
    char* Xs = (char*)XsBuf;
    char* Ws = (char*)WsBuf;

    int tid = threadIdx.x;
    int n0  = blockIdx.x * 128;
    int wave = tid >> 6, lane = tid & 63;
    int wm = wave >> 1, wn = wave & 1;
    int srow = tid >> 1, shalf = tid & 1;

    int nrow = n0 + srow;
    if (nrow >= N_NODES_C) nrow = N_NODES_C - 1;

    f32x4 acc[4][4];
#pragma unroll
    for (int i = 0; i < 4; ++i)
#pragma unroll
        for (int j = 0; j < 4; ++j) acc[i][j] = (f32x4)0.f;

#pragma unroll
    for (int k0 = 0; k0 < 384; k0 += 64) {
        const float* xsrc = (k0 < 128)
            ? (nfeats  + (size_t)nrow * 128 + k0         + shalf * 32)
            : (h_neigh + (size_t)nrow * 256 + (k0 - 128) + shalf * 32);
        stage_half_row(xsrc, Xs, srow, shalf);
        const float* wsrc = W + (size_t)srow * 384 + k0 + shalf * 32;
        stage_half_row(wsrc, Ws, srow, shalf);
        __syncthreads();
        mfma_slab(Xs, Ws, wm, wn, lane, acc);
        __syncthreads();
    }

    epilogue_store(acc, bias, out, n0, N_NODES_C, wm, wn, lane);
}

// ---------------------------------------------------------------------------
// pp_k: P = [h @ W1^T | h @ W2^T] in bf16, no bias/relu. K=128 (2 slabs).
// blockIdx.y = cb selects W cols [cb*128, cb*128+128).
// ---------------------------------------------------------------------------
__global__ __launch_bounds__(256) void pp_k(
    const float* __restrict__ h, const float* __restrict__ W,
    unsigned short* __restrict__ P)
{
    __shared__ uint4 XsBuf[1024];
    __shared__ uint4 WsBuf[1024];
    char* Xs = (char*)XsBuf;
    char* Ws = (char*)WsBuf;

    int tid = threadIdx.x;
    int n0  = blockIdx.x * 128;
    int cb  = blockIdx.y;
    int wave = tid >> 6, lane = tid & 63;
    int wm = wave >> 1, wn = wave & 1;
    int srow = tid >> 1, shalf = tid & 1;

    int nrow = n0 + srow;
    if (nrow >= N_NODES_C) nrow = N_NODES_C - 1;

    f32x4 acc[4][4];
#pragma unroll
    for (int i = 0; i < 4; ++i)
#pragma unroll
        for (int j = 0; j < 4; ++j) acc[i][j] = (f32x4)0.f;

#pragma unroll
    for (int k0 = 0; k0 < 128; k0 += 64) {
        const float* xsrc = h + (size_t)nrow * 128 + k0 + shalf * 32;
        stage_half_row(xsrc, Xs, srow, shalf);
        const float* wsrc = W + (size_t)srow * 256 + cb * 128 + k0 + shalf * 32;
        stage_half_row(wsrc, Ws, srow, shalf);
        __syncthreads();
        mfma_slab(Xs, Ws, wm, wn, lane, acc);
        __syncthreads();
    }

    int col0 = wn * 64 + (lane & 15);
    int row0 = n0 + wm * 64 + (lane >> 4) * 4;
#pragma unroll
    for (int j = 0; j < 4; ++j) {
#pragma unroll
        for (int i = 0; i < 4; ++i) {
#pragma unroll
            for (int r = 0; r < 4; ++r) {
                int row = row0 + i * 16 + r;
                if (row < N_NODES_C)
                    P[(size_t)row * 256 + cb * 128 + col0 + j * 16] = f2bf(acc[i][j][r]);
            }
        }
    }
}

// ---------------------------------------------------------------------------
// edge_add_k: out[e] = relu(P1[u[e]] + P2[v[e]] + b) for e >= EDGE_HEAD_ROWS.
// 32 lanes per edge row; ushort4 (8B) gathers, float4 store. Pure stream.
// ---------------------------------------------------------------------------
__global__ __launch_bounds__(256) void edge_add_k(
    const unsigned short* __restrict__ P, const int* __restrict__ u,
    const int* __restrict__ v, const float* __restrict__ bias,
    float* __restrict__ out)
{
    int c = blockIdx.x * 256 + threadIdx.x;
    int e = EDGE_HEAD_ROWS + (c >> 5);
    int q = c & 31;
    int uu = u[e], vv = v[e];
    ushort4 pa = *reinterpret_cast<const ushort4*>(P + (size_t)uu * 256 + q * 4);
    ushort4 pb = *reinterpret_cast<const ushort4*>(P + (size_t)vv * 256 + 128 + q * 4);
    float4 b4 = *reinterpret_cast<const float4*>(bias + q * 4);
    float4 o;
    o.x = fmaxf(bf2f(pa.x) + bf2f(pb.x) + b4.x, 0.f);
    o.y = fmaxf(bf2f(pa.y) + bf2f(pb.y) + b4.y, 0.f);
    o.z = fmaxf(bf2f(pa.z) + bf2f(pb.z) + b4.z, 0.f);
    o.w = fmaxf(bf2f(pa.w) + bf2f(pb.w) + b4.w, 0.f);
    *reinterpret_cast<float4*>(out + (size_t)e * 128 + q * 4) = o;
}

// ---------------------------------------------------------------------------
// edge_head_k: direct bf16-MFMA GEMM (R4 structure) for rows [0, EDGE_HEAD_ROWS);
// runs last, reads fp32 h + fp32 W (P already consumed).
// ---------------------------------------------------------------------------
__global__ __launch_bounds__(256) void edge_head_k(
    const float* __restrict__ h, const int* __restrict__ u,
    const int* __restrict__ v, const float* __restrict__ W,
    const float* __restrict__ bias, float* __restrict__ out)
{
    __shared__ uint4 XsBuf[1024];
    __shared__ uint4 WsBuf[1024];
    __shared__ int us[128], vs[128];
    char* Xs = (char*)XsBuf;
    char* Ws = (char*)WsBuf;

    int tid = threadIdx.x;
    int e0  = blockIdx.x * 128;
    if (tid < 128) us[tid]       = u[e0 + tid];
    else           vs[tid - 128] = v[e0 + tid - 128];
    __syncthreads();

    int wave = tid >> 6, lane = tid & 63;
    int wm = wave >> 1, wn = wave & 1;
    int srow = tid >> 1, shalf = tid & 1;

    f32x4 acc[4][4];
#pragma unroll
    for (int i = 0; i < 4; ++i)
#pragma unroll
        for (int j = 0; j < 4; ++j) acc[i][j] = (f32x4)0.f;

#pragma unroll
    for (int k0 = 0; k0 < 256; k0 += 64) {
        int node = (k0 < 128) ? us[srow] : vs[srow];
        const float* xsrc = h + (size_t)node * 128 + (k0 & 127) + shalf * 32;
        stage_half_row(xsrc, Xs, srow, shalf);
        const float* wsrc = W + (size_t)srow * 256 + k0 + shalf * 32;
        stage_half_row(wsrc, Ws, srow, shalf);
        __syncthreads();
        mfma_slab(Xs, Ws, wm, wn, lane, acc);
        __syncthreads();
    }

    epilogue_store(acc, bias, out, e0, N_EDGES_C, wm, wn, lane);
}

// ---------------------------------------------------------------------------
extern "C" void kernel_launch(void* const* d_in, const int* in_sizes, int n_in,
                              void* d_out, int out_size, void* d_ws, size_t ws_size,
                              hipStream_t stream)
{
    const float* nfeats    = (const float*)d_in[0];
    const float* efeats    = (const float*)d_in[1];
    const int*   u         = (const int*)d_in[2];
    const int*   v         = (const int*)d_in[3];
    const float* W_apply_w = (const float*)d_in[4];
    const float* W_apply_b = (const float*)d_in[5];
    const float* W_edge_w  = (const float*)d_in[6];
    const float* W_edge_b  = (const float*)d_in[7];

    float* out      = (float*)d_out;
    float* h_nodes  = out;                                // [50000][128]
    float* edge_out = out + (size_t)N_NODES_C * 128;      // [800000][128]

    // --- Overlays inside the 409.6 MB edge-output region ---
    // h_neigh: floats [0, 12.8M)  = rows [0, 100000)       dead after node_k
    // CSR:     floats [12.8M, ~15.4M) = rows [100000, ...) dead after aggregate_k
    // P bf16:  rows [0, 50000) (25.6 MB)                   written by pp_k,
    //          read by edge_add_k, destroyed by edge_head_k (runs last)
    float* scratch = edge_out;
    float* h_neigh = scratch;                              // 12.8M floats
    int*   cnt     = (int*)(scratch + 12800000);           // 50000
    int*   rowst   = cnt + N_NODES_C;                      // 50001
    int*   cursor  = rowst + N_NODES_C + 1;                // 50000
    int2*  pairs   = (int2*)(cursor + N_NODES_C + 2);      // 800000 int2
    unsigned short* P = (unsigned short*)edge_out;         // [50000][256] bf16

    hipMemsetAsync(cnt, 0, N_NODES_C * sizeof(int), stream);

    count_k<<<N_EDGES_C / 256, 256, 0, stream>>>(v, cnt);
    scan_k<<<1, 1024, 0, stream>>>(cnt, rowst, cursor);
    fill_k<<<N_EDGES_C / 256, 256, 0, stream>>>(v, u, cursor, pairs);
    aggregate_k<<<N_NODES_C, 256, 0, stream>>>(pairs, rowst, nfeats, efeats, h_neigh);

    node_k<<<(N_NODES_C + 127) / 128, 256, 0, stream>>>(
        nfeats, h_neigh, W_apply_w, W_apply_b, h_nodes);

    pp_k<<<dim3((N_NODES_C + 127) / 128, 2), 256, 0, stream>>>(
        h_nodes, W_edge_w, P);

    edge_add_k<<<EDGE_ADD_BLOCKS, 256, 0, stream>>>(
        P, u, v, W_edge_b, edge_out);

    edge_head_k<<<EDGE_HEAD_ROWS / 128, 256, 0, stream>>>(
        h_nodes, u, v, W_edge_w, W_edge_b, edge_out);
}

// Round 7
// 562.188 us; speedup vs baseline: 1.4287x; 1.0052x over previous
//
#include <hip/hip_runtime.h>
#include <hip/hip_bf16.h>

#define N_NODES_C 50000
#define N_EDGES_C 800000
// P (bf16 [50000][256]) overlays edge-output rows [0, 50000). edge_add_k
// writes rows [EDGE_HEAD_ROWS, 800000); edge_head_k (direct GEMM) computes
// rows [0, EDGE_HEAD_ROWS) last, after P is dead.
#define EDGE_HEAD_ROWS 50048             // 391 * 128
#define EDGE_ADD_BLOCKS 93744            // (800000-50048)*32/256

typedef __attribute__((ext_vector_type(8))) short bf16x8;
typedef __attribute__((ext_vector_type(4))) float f32x4;

__device__ __forceinline__ unsigned short f2bf(float f) {
    unsigned int x = __float_as_uint(f);
    unsigned int r = x + 0x7fffu + ((x >> 16) & 1u);   // RNE
    return (unsigned short)(r >> 16);
}
__device__ __forceinline__ float bf2f(unsigned short s) {
    return __uint_as_float(((unsigned int)s) << 16);
}

// ---------------------------------------------------------------------------
// zero_k: replaces hipMemsetAsync(cnt) — the runtime fillBuffer kernel was
// costing ~252 µs/call (rocprof R6: one fillBufferAligned per replay, ~0
// traffic, 11% occupancy). 196 blocks x 256 thr, one int each: ~3 µs.
// ---------------------------------------------------------------------------
__global__ __launch_bounds__(256) void zero_k(int* __restrict__ cnt)
{
    int i = blockIdx.x * 256 + threadIdx.x;
    if (i < N_NODES_C) cnt[i] = 0;
}

// ---------------------------------------------------------------------------
// CSR build: count -> scan -> fill
// ---------------------------------------------------------------------------
__global__ __launch_bounds__(256) void count_k(const int* __restrict__ v, int* __restrict__ cnt)
{
    int e = blockIdx.x * 256 + threadIdx.x;
    atomicAdd(&cnt[v[e]], 1);
}

__global__ __launch_bounds__(1024) void scan_k(const int* __restrict__ cnt,
                                               int* __restrict__ rowst,
                                               int* __restrict__ cursor)
{
    __shared__ int wsum[16];
    int tid = threadIdx.x, lane = tid & 63, wid = tid >> 6;
    int carry = 0;
    for (int base = 0; base < N_NODES_C; base += 1024) {
        int i = base + tid;
        int x = (i < N_NODES_C) ? cnt[i] : 0;
        int s = x;
#pragma unroll
        for (int d = 1; d < 64; d <<= 1) {
            int t = __shfl_up(s, d, 64);
            if (lane >= d) s += t;
        }
        if (lane == 63) wsum[wid] = s;
        __syncthreads();
        if (wid == 0) {
            int w = (lane < 16) ? wsum[lane] : 0;
#pragma unroll
            for (int d = 1; d < 16; d <<= 1) {
                int t = __shfl_up(w, d, 64);
                if (lane >= d) w += t;
            }
            if (lane < 16) wsum[lane] = w;
        }
        __syncthreads();
        int offset = carry + (wid > 0 ? wsum[wid - 1] : 0);
        int excl = offset + s - x;
        if (i < N_NODES_C) { rowst[i] = excl; cursor[i] = excl; }
        carry += wsum[15];
        __syncthreads();
    }
    if (tid == 0) rowst[N_NODES_C] = carry;
}

__global__ __launch_bounds__(256) void fill_k(const int* __restrict__ v,
                                              const int* __restrict__ u,
                                              int* __restrict__ cursor,
                                              int2* __restrict__ pairs)
{
    int e = blockIdx.x * 256 + threadIdx.x;
    int pos = atomicAdd(&cursor[v[e]], 1);
    pairs[pos] = make_int2(e, u[e]);
}

// ---------------------------------------------------------------------------
// Aggregate: one block per dst node; 4 edge-groups of 64 lanes, float4/lane.
// ---------------------------------------------------------------------------
__global__ __launch_bounds__(256) void aggregate_k(
    const int2* __restrict__ pairs, const int* __restrict__ rowst,
    const float* __restrict__ nfeats, const float* __restrict__ efeats,
    float* __restrict__ h_neigh)
{
    __shared__ float4 red[256];
    int n = blockIdx.x, tid = threadIdx.x;
    int grp = tid >> 6, lane = tid & 63;
    int s = rowst[n], e_end = rowst[n + 1];
    int deg = e_end - s;

    float4 acc = make_float4(0.f, 0.f, 0.f, 0.f);
    for (int i = s + grp; i < e_end; i += 4) {
        int2 p = pairs[i];
        const float* src = (lane < 32)
            ? (nfeats + (size_t)p.y * 128 + lane * 4)
            : (efeats + (size_t)p.x * 128 + (lane - 32) * 4);
        float4 vv = *reinterpret_cast<const float4*>(src);
        acc.x += vv.x; acc.y += vv.y; acc.z += vv.z; acc.w += vv.w;
    }
    red[tid] = acc;
    __syncthreads();
    if (grp == 0) {
        float4 a = red[lane], b = red[64 + lane], c = red[128 + lane], d = red[192 + lane];
        float r = (deg > 0) ? 1.f / (float)deg : 0.f;
        float4 o;
        o.x = (a.x + b.x + c.x + d.x) * r;
        o.y = (a.y + b.y + c.y + d.y) * r;
        o.z = (a.z + b.z + c.z + d.z) * r;
        o.w = (a.w + b.w + c.w + d.w) * r;
        *reinterpret_cast<float4*>(h_neigh + (size_t)n * 256 + lane * 4) = o;
    }
}

// ---------------------------------------------------------------------------
// bf16-MFMA tile machinery. LDS [128 rows][64 k] bf16, swizzle
// byte ^= (row&7)<<4.
// ---------------------------------------------------------------------------
__device__ __forceinline__ void stage_half_row(
    const float* __restrict__ src, char* __restrict__ lds, int row, int halfg)
{
#pragma unroll
    for (int g = 0; g < 4; ++g) {
        float4 f0 = reinterpret_cast<const float4*>(src)[g * 2 + 0];
        float4 f1 = reinterpret_cast<const float4*>(src)[g * 2 + 1];
        union { unsigned short s[8]; uint4 q; } pk;
        pk.s[0] = f2bf(f0.x); pk.s[1] = f2bf(f0.y);
        pk.s[2] = f2bf(f0.z); pk.s[3] = f2bf(f0.w);
        pk.s[4] = f2bf(f1.x); pk.s[5] = f2bf(f1.y);
        pk.s[6] = f2bf(f1.z); pk.s[7] = f2bf(f1.w);
        int byteoff = ((halfg * 4 + g) * 16) ^ ((row & 7) << 4);
        *reinterpret_cast<uint4*>(lds + row * 128 + byteoff) = pk.q;
    }
}

__device__ __forceinline__ void mfma_slab(
    const char* __restrict__ Xs, const char* __restrict__ Ws,
    int wm, int wn, int lane, f32x4 (&acc)[4][4])
{
#pragma unroll
    for (int c = 0; c < 2; ++c) {
        int kb = c * 64 + (lane >> 4) * 16;
        bf16x8 a[4], b[4];
#pragma unroll
        for (int i = 0; i < 4; ++i) {
            int row = wm * 64 + i * 16 + (lane & 15);
            a[i] = *reinterpret_cast<const bf16x8*>(
                Xs + row * 128 + (kb ^ ((row & 7) << 4)));
        }
#pragma unroll
        for (int j = 0; j < 4; ++j) {
            int row = wn * 64 + j * 16 + (lane & 15);
            b[j] = *reinterpret_cast<const bf16x8*>(
                Ws + row * 128 + (kb ^ ((row & 7) << 4)));
        }
#pragma unroll
        for (int i = 0; i < 4; ++i)
#pragma unroll
            for (int j = 0; j < 4; ++j)
                acc[i][j] = __builtin_amdgcn_mfma_f32_16x16x32_bf16(
                    a[i], b[j], acc[i][j], 0, 0, 0);
    }
}

__device__ __forceinline__ void epilogue_store(
    const f32x4 (&acc)[4][4], const float* __restrict__ bias,
    float* __restrict__ out, int row_base, int row_limit, int wm, int wn, int lane)
{
    int col0 = wn * 64 + (lane & 15);
    int row0 = row_base + wm * 64 + (lane >> 4) * 4;
#pragma unroll
    for (int j = 0; j < 4; ++j) {
        float bj = bias[col0 + j * 16];
#pragma unroll
        for (int i = 0; i < 4; ++i) {
#pragma unroll
            for (int r = 0; r < 4; ++r) {
                int row = row0 + i * 16 + r;
                if (row < row_limit) {
                    float val = fmaxf(acc[i][j][r] + bj, 0.f);
                    out[(size_t)row * 128 + col0 + j * 16] = val;
                }
            }
        }
    }
}

// ---------------------------------------------------------------------------
// K2: node update via bf16 MFMA. K=384, 6 slabs.
// ---------------------------------------------------------------------------
__global__ __launch_bounds__(256) void node_k(
    const float* __restrict__ nfeats, const float* __restrict__ h_neigh,
    const float* __restrict__ W, const float* __restrict__ bias,
    float* __restrict__ out)
{
    __shared__ uint4 XsBuf[1024];
    __shared__ uint4 WsBuf[1024];
    char* Xs = (char*)XsBuf;
    char* Ws = (char*)WsBuf;

    int tid = threadIdx.x;
    int n0  = blockIdx.x * 128;
    int wave = tid >> 6, lane = tid & 63;
    int wm = wave >> 1, wn = wave & 1;
    int srow = tid >> 1, shalf = tid & 1;

    int nrow = n0 + srow;
    if (nrow >= N_NODES_C) nrow = N_NODES_C - 1;

    f32x4 acc[4][4];
#pragma unroll
    for (int i = 0; i < 4; ++i)
#pragma unroll
        for (int j = 0; j < 4; ++j) acc[i][j] = (f32x4)0.f;

#pragma unroll
    for (int k0 = 0; k0 < 384; k0 += 64) {
        const float* xsrc = (k0 < 128)
            ? (nfeats  + (size_t)nrow * 128 + k0         + shalf * 32)
            : (h_neigh + (size_t)nrow * 256 + (k0 - 128) + shalf * 32);
        stage_half_row(xsrc, Xs, srow, shalf);
        const float* wsrc = W + (size_t)srow * 384 + k0 + shalf * 32;
        stage_half_row(wsrc, Ws, srow, shalf);
        __syncthreads();
        mfma_slab(Xs, Ws, wm, wn, lane, acc);
        __syncthreads();
    }

    epilogue_store(acc, bias, out, n0, N_NODES_C, wm, wn, lane);
}

// ---------------------------------------------------------------------------
// pp_k: P = [h @ W1^T | h @ W2^T] in bf16, no bias/relu. K=128 (2 slabs).
// blockIdx.y = cb selects W cols [cb*128, cb*128+128).
// ---------------------------------------------------------------------------
__global__ __launch_bounds__(256) void pp_k(
    const float* __restrict__ h, const float* __restrict__ W,
    unsigned short* __restrict__ P)
{
    __shared__ uint4 XsBuf[1024];
    __shared__ uint4 WsBuf[1024];
    char* Xs = (char*)XsBuf;
    char* Ws = (char*)WsBuf;

    int tid = threadIdx.x;
    int n0  = blockIdx.x * 128;
    int cb  = blockIdx.y;
    int wave = tid >> 6, lane = tid & 63;
    int wm = wave >> 1, wn = wave & 1;
    int srow = tid >> 1, shalf = tid & 1;

    int nrow = n0 + srow;
    if (nrow >= N_NODES_C) nrow = N_NODES_C - 1;

    f32x4 acc[4][4];
#pragma unroll
    for (int i = 0; i < 4; ++i)
#pragma unroll
        for (int j = 0; j < 4; ++j) acc[i][j] = (f32x4)0.f;

#pragma unroll
    for (int k0 = 0; k0 < 128; k0 += 64) {
        const float* xsrc = h + (size_t)nrow * 128 + k0 + shalf * 32;
        stage_half_row(xsrc, Xs, srow, shalf);
        const float* wsrc = W + (size_t)srow * 256 + cb * 128 + k0 + shalf * 32;
        stage_half_row(wsrc, Ws, srow, shalf);
        __syncthreads();
        mfma_slab(Xs, Ws, wm, wn, lane, acc);
        __syncthreads();
    }

    int col0 = wn * 64 + (lane & 15);
    int row0 = n0 + wm * 64 + (lane >> 4) * 4;
#pragma unroll
    for (int j = 0; j < 4; ++j) {
#pragma unroll
        for (int i = 0; i < 4; ++i) {
#pragma unroll
            for (int r = 0; r < 4; ++r) {
                int row = row0 + i * 16 + r;
                if (row < N_NODES_C)
                    P[(size_t)row * 256 + cb * 128 + col0 + j * 16] = f2bf(acc[i][j][r]);
            }
        }
    }
}

// ---------------------------------------------------------------------------
// edge_add_k: out[e] = relu(P1[u[e]] + P2[v[e]] + b) for e >= EDGE_HEAD_ROWS.
// 32 lanes per edge row; ushort4 (8B) gathers, float4 store. Pure stream.
// ---------------------------------------------------------------------------
__global__ __launch_bounds__(256) void edge_add_k(
    const unsigned short* __restrict__ P, const int* __restrict__ u,
    const int* __restrict__ v, const float* __restrict__ bias,
    float* __restrict__ out)
{
    int c = blockIdx.x * 256 + threadIdx.x;
    int e = EDGE_HEAD_ROWS + (c >> 5);
    int q = c & 31;
    int uu = u[e], vv = v[e];
    ushort4 pa = *reinterpret_cast<const ushort4*>(P + (size_t)uu * 256 + q * 4);
    ushort4 pb = *reinterpret_cast<const ushort4*>(P + (size_t)vv * 256 + 128 + q * 4);
    float4 b4 = *reinterpret_cast<const float4*>(bias + q * 4);
    float4 o;
    o.x = fmaxf(bf2f(pa.x) + bf2f(pb.x) + b4.x, 0.f);
    o.y = fmaxf(bf2f(pa.y) + bf2f(pb.y) + b4.y, 0.f);
    o.z = fmaxf(bf2f(pa.z) + bf2f(pb.z) + b4.z, 0.f);
    o.w = fmaxf(bf2f(pa.w) + bf2f(pb.w) + b4.w, 0.f);
    *reinterpret_cast<float4*>(out + (size_t)e * 128 + q * 4) = o;
}

// ---------------------------------------------------------------------------
// edge_head_k: direct bf16-MFMA GEMM for rows [0, EDGE_HEAD_ROWS);
// runs last, reads fp32 h + fp32 W (P already consumed).
// ---------------------------------------------------------------------------
__global__ __launch_bounds__(256) void edge_head_k(
    const float* __restrict__ h, const int* __restrict__ u,
    const int* __restrict__ v, const float* __restrict__ W,
    const float* __restrict__ bias, float* __restrict__ out)
{
    __shared__ uint4 XsBuf[1024];
    __shared__ uint4 WsBuf[1024];
    __shared__ int us[128], vs[128];
    char* Xs = (char*)XsBuf;
    char* Ws = (char*)WsBuf;

    int tid = threadIdx.x;
    int e0  = blockIdx.x * 128;
    if (tid < 128) us[tid]       = u[e0 + tid];
    else           vs[tid - 128] = v[e0 + tid - 128];
    __syncthreads();

    int wave = tid >> 6, lane = tid & 63;
    int wm = wave >> 1, wn = wave & 1;
    int srow = tid >> 1, shalf = tid & 1;

    f32x4 acc[4][4];
#pragma unroll
    for (int i = 0; i < 4; ++i)
#pragma unroll
        for (int j = 0; j < 4; ++j) acc[i][j] = (f32x4)0.f;

#pragma unroll
    for (int k0 = 0; k0 < 256; k0 += 64) {
        int node = (k0 < 128) ? us[srow] : vs[srow];
        const float* xsrc = h + (size_t)node * 128 + (k0 & 127) + shalf * 32;
        stage_half_row(xsrc, Xs, srow, shalf);
        const float* wsrc = W + (size_t)srow * 256 + k0 + shalf * 32;
        stage_half_row(wsrc, Ws, srow, shalf);
        __syncthreads();
        mfma_slab(Xs, Ws, wm, wn, lane, acc);
        __syncthreads();
    }

    epilogue_store(acc, bias, out, e0, N_EDGES_C, wm, wn, lane);
}

// ---------------------------------------------------------------------------
extern "C" void kernel_launch(void* const* d_in, const int* in_sizes, int n_in,
                              void* d_out, int out_size, void* d_ws, size_t ws_size,
                              hipStream_t stream)
{
    const float* nfeats    = (const float*)d_in[0];
    const float* efeats    = (const float*)d_in[1];
    const int*   u         = (const int*)d_in[2];
    const int*   v         = (const int*)d_in[3];
    const float* W_apply_w = (const float*)d_in[4];
    const float* W_apply_b = (const float*)d_in[5];
    const float* W_edge_w  = (const float*)d_in[6];
    const float* W_edge_b  = (const float*)d_in[7];

    float* out      = (float*)d_out;
    float* h_nodes  = out;                                // [50000][128]
    float* edge_out = out + (size_t)N_NODES_C * 128;      // [800000][128]

    // --- Overlays inside the 409.6 MB edge-output region ---
    float* scratch = edge_out;
    float* h_neigh = scratch;                              // 12.8M floats
    int*   cnt     = (int*)(scratch + 12800000);           // 50000
    int*   rowst   = cnt + N_NODES_C;                      // 50001
    int*   cursor  = rowst + N_NODES_C + 1;                // 50000
    int2*  pairs   = (int2*)(cursor + N_NODES_C + 2);      // 800000 int2
    unsigned short* P = (unsigned short*)edge_out;         // [50000][256] bf16

    zero_k<<<(N_NODES_C + 255) / 256, 256, 0, stream>>>(cnt);

    count_k<<<N_EDGES_C / 256, 256, 0, stream>>>(v, cnt);
    scan_k<<<1, 1024, 0, stream>>>(cnt, rowst, cursor);
    fill_k<<<N_EDGES_C / 256, 256, 0, stream>>>(v, u, cursor, pairs);
    aggregate_k<<<N_NODES_C, 256, 0, stream>>>(pairs, rowst, nfeats, efeats, h_neigh);

    node_k<<<(N_NODES_C + 127) / 128, 256, 0, stream>>>(
        nfeats, h_neigh, W_apply_w, W_apply_b, h_nodes);

    pp_k<<<dim3((N_NODES_C + 127) / 128, 2), 256, 0, stream>>>(
        h_nodes, W_edge_w, P);

    edge_add_k<<<EDGE_ADD_BLOCKS, 256, 0, stream>>>(
        P, u, v, W_edge_b, edge_out);

    edge_head_k<<<EDGE_HEAD_ROWS / 128, 256, 0, stream>>>(
        h_nodes, u, v, W_edge_w, W_edge_b, edge_out);
}

// Round 8
// 448.855 us; speedup vs baseline: 1.7894x; 1.2525x over previous
//
#include <hip/hip_runtime.h>
#include <hip/hip_bf16.h>

#define N_NODES_C 50000
#define N_EDGES_C 800000
#define NBLK_NODES 196                   // ceil(50000/256)
// Fallback overlay (only if ws_size too small): P overlays edge rows
// [0,50000); edge_add covers [EDGE_HEAD_ROWS,800000), edge_head the rest.
#define EDGE_HEAD_ROWS 50048             // 391 * 128

typedef __attribute__((ext_vector_type(8))) short bf16x8;
typedef __attribute__((ext_vector_type(4))) float f32x4;

__device__ __forceinline__ unsigned short f2bf(float f) {
    unsigned int x = __float_as_uint(f);
    unsigned int r = x + 0x7fffu + ((x >> 16) & 1u);   // RNE
    return (unsigned short)(r >> 16);
}
__device__ __forceinline__ float bf2f(unsigned short s) {
    return __uint_as_float(((unsigned int)s) << 16);
}

// ---------------------------------------------------------------------------
__global__ __launch_bounds__(256) void zero_k(int* __restrict__ cnt)
{
    int i = blockIdx.x * 256 + threadIdx.x;
    if (i < N_NODES_C) cnt[i] = 0;
}

__global__ __launch_bounds__(256) void count_k(const int* __restrict__ v, int* __restrict__ cnt)
{
    int e = blockIdx.x * 256 + threadIdx.x;
    atomicAdd(&cnt[v[e]], 1);
}

// ---------------------------------------------------------------------------
// Parallel scan: partial block sums -> 1-block scan of 196 -> scatter.
// (replaces the single-block 49-iteration scan: ~0.4% machine occupancy)
// ---------------------------------------------------------------------------
__global__ __launch_bounds__(256) void scan_partial_k(
    const int* __restrict__ cnt, int* __restrict__ bsum)
{
    __shared__ int ws[4];
    int b = blockIdx.x, t = threadIdx.x, lane = t & 63, wid = t >> 6;
    int i = b * 256 + t;
    int x = (i < N_NODES_C) ? cnt[i] : 0;
    int s = x;
#pragma unroll
    for (int d = 1; d < 64; d <<= 1) {
        int tv = __shfl_up(s, d, 64);
        if (lane >= d) s += tv;
    }
    if (lane == 63) ws[wid] = s;
    __syncthreads();
    if (t == 0) bsum[b] = ws[0] + ws[1] + ws[2] + ws[3];
}

__global__ __launch_bounds__(256) void scan_block_k(
    const int* __restrict__ bsum, int* __restrict__ boff, int* __restrict__ rowst)
{
    __shared__ int ws[4];
    int t = threadIdx.x, lane = t & 63, wid = t >> 6;
    int x = (t < NBLK_NODES) ? bsum[t] : 0;
    int s = x;
#pragma unroll
    for (int d = 1; d < 64; d <<= 1) {
        int tv = __shfl_up(s, d, 64);
        if (lane >= d) s += tv;
    }
    if (lane == 63) ws[wid] = s;
    __syncthreads();
    if (t == 0) {
        int a = 0;
#pragma unroll
        for (int w = 0; w < 4; ++w) { int tmp = ws[w]; ws[w] = a; a += tmp; }
    }
    __syncthreads();
    int excl = ws[wid] + s - x;
    if (t < NBLK_NODES) boff[t] = excl;
    if (t == 255) rowst[N_NODES_C] = excl;   // x==0 above 195 -> excl == total
}

__global__ __launch_bounds__(256) void scan_scatter_k(
    const int* __restrict__ cnt, const int* __restrict__ boff,
    int* __restrict__ rowst, int* __restrict__ cursor)
{
    __shared__ int ws[4];
    int b = blockIdx.x, t = threadIdx.x, lane = t & 63, wid = t >> 6;
    int i = b * 256 + t;
    int x = (i < N_NODES_C) ? cnt[i] : 0;
    int s = x;
#pragma unroll
    for (int d = 1; d < 64; d <<= 1) {
        int tv = __shfl_up(s, d, 64);
        if (lane >= d) s += tv;
    }
    if (lane == 63) ws[wid] = s;
    __syncthreads();
    if (t == 0) {
        int a = 0;
#pragma unroll
        for (int w = 0; w < 4; ++w) { int tmp = ws[w]; ws[w] = a; a += tmp; }
    }
    __syncthreads();
    int excl = boff[b] + ws[wid] + s - x;
    if (i < N_NODES_C) { rowst[i] = excl; cursor[i] = excl; }
}

__global__ __launch_bounds__(256) void fill_k(const int* __restrict__ v,
                                              const int* __restrict__ u,
                                              int* __restrict__ cursor,
                                              int2* __restrict__ pairs)
{
    int e = blockIdx.x * 256 + threadIdx.x;
    int pos = atomicAdd(&cursor[v[e]], 1);
    pairs[pos] = make_int2(e, u[e]);
}

// ---------------------------------------------------------------------------
// Aggregate: one block per dst node; 4 groups x unroll-2 = 8 edges in flight.
// ---------------------------------------------------------------------------
__global__ __launch_bounds__(256) void aggregate_k(
    const int2* __restrict__ pairs, const int* __restrict__ rowst,
    const float* __restrict__ nfeats, const float* __restrict__ efeats,
    float* __restrict__ h_neigh)
{
    __shared__ float4 red[256];
    int n = blockIdx.x, tid = threadIdx.x;
    int grp = tid >> 6, lane = tid & 63;
    int s = rowst[n], e_end = rowst[n + 1];
    int deg = e_end - s;

    float4 acc = make_float4(0.f, 0.f, 0.f, 0.f);
    float4 acc2 = make_float4(0.f, 0.f, 0.f, 0.f);
    int i = s + grp;
    for (; i + 4 < e_end; i += 8) {
        int2 pA = pairs[i];
        int2 pB = pairs[i + 4];
        const float* srcA = (lane < 32)
            ? (nfeats + (size_t)pA.y * 128 + lane * 4)
            : (efeats + (size_t)pA.x * 128 + (lane - 32) * 4);
        const float* srcB = (lane < 32)
            ? (nfeats + (size_t)pB.y * 128 + lane * 4)
            : (efeats + (size_t)pB.x * 128 + (lane - 32) * 4);
        float4 a4 = *reinterpret_cast<const float4*>(srcA);
        float4 b4 = *reinterpret_cast<const float4*>(srcB);
        acc.x += a4.x; acc.y += a4.y; acc.z += a4.z; acc.w += a4.w;
        acc2.x += b4.x; acc2.y += b4.y; acc2.z += b4.z; acc2.w += b4.w;
    }
    if (i < e_end) {
        int2 p = pairs[i];
        const float* src = (lane < 32)
            ? (nfeats + (size_t)p.y * 128 + lane * 4)
            : (efeats + (size_t)p.x * 128 + (lane - 32) * 4);
        float4 vv = *reinterpret_cast<const float4*>(src);
        acc.x += vv.x; acc.y += vv.y; acc.z += vv.z; acc.w += vv.w;
    }
    acc.x += acc2.x; acc.y += acc2.y; acc.z += acc2.z; acc.w += acc2.w;
    red[tid] = acc;
    __syncthreads();
    if (grp == 0) {
        float4 a = red[lane], b = red[64 + lane], c = red[128 + lane], d = red[192 + lane];
        float r = (deg > 0) ? 1.f / (float)deg : 0.f;
        float4 o;
        o.x = (a.x + b.x + c.x + d.x) * r;
        o.y = (a.y + b.y + c.y + d.y) * r;
        o.z = (a.z + b.z + c.z + d.z) * r;
        o.w = (a.w + b.w + c.w + d.w) * r;
        *reinterpret_cast<float4*>(h_neigh + (size_t)n * 256 + lane * 4) = o;
    }
}

// ---------------------------------------------------------------------------
// bf16-MFMA tile machinery (LDS [128][64] bf16, byte ^= (row&7)<<4).
// ---------------------------------------------------------------------------
__device__ __forceinline__ void stage_half_row(
    const float* __restrict__ src, char* __restrict__ lds, int row, int halfg)
{
#pragma unroll
    for (int g = 0; g < 4; ++g) {
        float4 f0 = reinterpret_cast<const float4*>(src)[g * 2 + 0];
        float4 f1 = reinterpret_cast<const float4*>(src)[g * 2 + 1];
        union { unsigned short s[8]; uint4 q; } pk;
        pk.s[0] = f2bf(f0.x); pk.s[1] = f2bf(f0.y);
        pk.s[2] = f2bf(f0.z); pk.s[3] = f2bf(f0.w);
        pk.s[4] = f2bf(f1.x); pk.s[5] = f2bf(f1.y);
        pk.s[6] = f2bf(f1.z); pk.s[7] = f2bf(f1.w);
        int byteoff = ((halfg * 4 + g) * 16) ^ ((row & 7) << 4);
        *reinterpret_cast<uint4*>(lds + row * 128 + byteoff) = pk.q;
    }
}

__device__ __forceinline__ void mfma_slab(
    const char* __restrict__ Xs, const char* __restrict__ Ws,
    int wm, int wn, int lane, f32x4 (&acc)[4][4])
{
#pragma unroll
    for (int c = 0; c < 2; ++c) {
        int kb = c * 64 + (lane >> 4) * 16;
        bf16x8 a[4], b[4];
#pragma unroll
        for (int i = 0; i < 4; ++i) {
            int row = wm * 64 + i * 16 + (lane & 15);
            a[i] = *reinterpret_cast<const bf16x8*>(
                Xs + row * 128 + (kb ^ ((row & 7) << 4)));
        }
#pragma unroll
        for (int j = 0; j < 4; ++j) {
            int row = wn * 64 + j * 16 + (lane & 15);
            b[j] = *reinterpret_cast<const bf16x8*>(
                Ws + row * 128 + (kb ^ ((row & 7) << 4)));
        }
#pragma unroll
        for (int i = 0; i < 4; ++i)
#pragma unroll
            for (int j = 0; j < 4; ++j)
                acc[i][j] = __builtin_amdgcn_mfma_f32_16x16x32_bf16(
                    a[i], b[j], acc[i][j], 0, 0, 0);
    }
}

__device__ __forceinline__ void epilogue_store(
    const f32x4 (&acc)[4][4], const float* __restrict__ bias,
    float* __restrict__ out, int row_base, int row_limit, int wm, int wn, int lane)
{
    int col0 = wn * 64 + (lane & 15);
    int row0 = row_base + wm * 64 + (lane >> 4) * 4;
#pragma unroll
    for (int j = 0; j < 4; ++j) {
        float bj = bias[col0 + j * 16];
#pragma unroll
        for (int i = 0; i < 4; ++i) {
#pragma unroll
            for (int r = 0; r < 4; ++r) {
                int row = row0 + i * 16 + r;
                if (row < row_limit) {
                    float val = fmaxf(acc[i][j][r] + bj, 0.f);
                    out[(size_t)row * 128 + col0 + j * 16] = val;
                }
            }
        }
    }
}

// ---------------------------------------------------------------------------
// node_k: bf16 MFMA, K=384 (6 slabs).
// ---------------------------------------------------------------------------
__global__ __launch_bounds__(256) void node_k(
    const float* __restrict__ nfeats, const float* __restrict__ h_neigh,
    const float* __restrict__ W, const float* __restrict__ bias,
    float* __restrict__ out)
{
    __shared__ uint4 XsBuf[1024];
    __shared__ uint4 WsBuf[1024];
    char* Xs = (char*)XsBuf;
    char* Ws = (char*)WsBuf;

    int tid = threadIdx.x;
    int n0  = blockIdx.x * 128;
    int wave = tid >> 6, lane = tid & 63;
    int wm = wave >> 1, wn = wave & 1;
    int srow = tid >> 1, shalf = tid & 1;

    int nrow = n0 + srow;
    if (nrow >= N_NODES_C) nrow = N_NODES_C - 1;

    f32x4 acc[4][4];
#pragma unroll
    for (int i = 0; i < 4; ++i)
#pragma unroll
        for (int j = 0; j < 4; ++j) acc[i][j] = (f32x4)0.f;

#pragma unroll
    for (int k0 = 0; k0 < 384; k0 += 64) {
        const float* xsrc = (k0 < 128)
            ? (nfeats  + (size_t)nrow * 128 + k0         + shalf * 32)
            : (h_neigh + (size_t)nrow * 256 + (k0 - 128) + shalf * 32);
        stage_half_row(xsrc, Xs, srow, shalf);
        const float* wsrc = W + (size_t)srow * 384 + k0 + shalf * 32;
        stage_half_row(wsrc, Ws, srow, shalf);
        __syncthreads();
        mfma_slab(Xs, Ws, wm, wn, lane, acc);
        __syncthreads();
    }

    epilogue_store(acc, bias, out, n0, N_NODES_C, wm, wn, lane);
}

// ---------------------------------------------------------------------------
// pp_k: P = [h @ W1^T | h @ W2^T] bf16, no bias/relu. blockIdx.y = col half.
// ---------------------------------------------------------------------------
__global__ __launch_bounds__(256) void pp_k(
    const float* __restrict__ h, const float* __restrict__ W,
    unsigned short* __restrict__ P)
{
    __shared__ uint4 XsBuf[1024];
    __shared__ uint4 WsBuf[1024];
    char* Xs = (char*)XsBuf;
    char* Ws = (char*)WsBuf;

    int tid = threadIdx.x;
    int n0  = blockIdx.x * 128;
    int cb  = blockIdx.y;
    int wave = tid >> 6, lane = tid & 63;
    int wm = wave >> 1, wn = wave & 1;
    int srow = tid >> 1, shalf = tid & 1;

    int nrow = n0 + srow;
    if (nrow >= N_NODES_C) nrow = N_NODES_C - 1;

    f32x4 acc[4][4];
#pragma unroll
    for (int i = 0; i < 4; ++i)
#pragma unroll
        for (int j = 0; j < 4; ++j) acc[i][j] = (f32x4)0.f;

#pragma unroll
    for (int k0 = 0; k0 < 128; k0 += 64) {
        const float* xsrc = h + (size_t)nrow * 128 + k0 + shalf * 32;
        stage_half_row(xsrc, Xs, srow, shalf);
        const float* wsrc = W + (size_t)srow * 256 + cb * 128 + k0 + shalf * 32;
        stage_half_row(wsrc, Ws, srow, shalf);
        __syncthreads();
        mfma_slab(Xs, Ws, wm, wn, lane, acc);
        __syncthreads();
    }

    int col0 = wn * 64 + (lane & 15);
    int row0 = n0 + wm * 64 + (lane >> 4) * 4;
#pragma unroll
    for (int j = 0; j < 4; ++j) {
#pragma unroll
        for (int i = 0; i < 4; ++i) {
#pragma unroll
            for (int r = 0; r < 4; ++r) {
                int row = row0 + i * 16 + r;
                if (row < N_NODES_C)
                    P[(size_t)row * 256 + cb * 128 + col0 + j * 16] = f2bf(acc[i][j][r]);
            }
        }
    }
}

// ---------------------------------------------------------------------------
// edge_add_k: out[e] = relu(P1[u[e]] + P2[v[e]] + b), e in [e_base, 800000).
// ---------------------------------------------------------------------------
__global__ __launch_bounds__(256) void edge_add_k(
    const unsigned short* __restrict__ P, const int* __restrict__ u,
    const int* __restrict__ v, const float* __restrict__ bias,
    float* __restrict__ out, int e_base)
{
    int c = blockIdx.x * 256 + threadIdx.x;
    int e = e_base + (c >> 5);
    int q = c & 31;
    int uu = u[e], vv = v[e];
    ushort4 pa = *reinterpret_cast<const ushort4*>(P + (size_t)uu * 256 + q * 4);
    ushort4 pb = *reinterpret_cast<const ushort4*>(P + (size_t)vv * 256 + 128 + q * 4);
    float4 b4 = *reinterpret_cast<const float4*>(bias + q * 4);
    float4 o;
    o.x = fmaxf(bf2f(pa.x) + bf2f(pb.x) + b4.x, 0.f);
    o.y = fmaxf(bf2f(pa.y) + bf2f(pb.y) + b4.y, 0.f);
    o.z = fmaxf(bf2f(pa.z) + bf2f(pb.z) + b4.z, 0.f);
    o.w = fmaxf(bf2f(pa.w) + bf2f(pb.w) + b4.w, 0.f);
    *reinterpret_cast<float4*>(out + (size_t)e * 128 + q * 4) = o;
}

// ---------------------------------------------------------------------------
// edge_head_k: direct bf16-MFMA GEMM for rows [0, EDGE_HEAD_ROWS) —
// FALLBACK path only (P overlaid on output; runs last).
// ---------------------------------------------------------------------------
__global__ __launch_bounds__(256) void edge_head_k(
    const float* __restrict__ h, const int* __restrict__ u,
    const int* __restrict__ v, const float* __restrict__ W,
    const float* __restrict__ bias, float* __restrict__ out)
{
    __shared__ uint4 XsBuf[1024];
    __shared__ uint4 WsBuf[1024];
    __shared__ int us[128], vs[128];
    char* Xs = (char*)XsBuf;
    char* Ws = (char*)WsBuf;

    int tid = threadIdx.x;
    int e0  = blockIdx.x * 128;
    if (tid < 128) us[tid]       = u[e0 + tid];
    else           vs[tid - 128] = v[e0 + tid - 128];
    __syncthreads();

    int wave = tid >> 6, lane = tid & 63;
    int wm = wave >> 1, wn = wave & 1;
    int srow = tid >> 1, shalf = tid & 1;

    f32x4 acc[4][4];
#pragma unroll
    for (int i = 0; i < 4; ++i)
#pragma unroll
        for (int j = 0; j < 4; ++j) acc[i][j] = (f32x4)0.f;

#pragma unroll
    for (int k0 = 0; k0 < 256; k0 += 64) {
        int node = (k0 < 128) ? us[srow] : vs[srow];
        const float* xsrc = h + (size_t)node * 128 + (k0 & 127) + shalf * 32;
        stage_half_row(xsrc, Xs, srow, shalf);
        const float* wsrc = W + (size_t)srow * 256 + k0 + shalf * 32;
        stage_half_row(wsrc, Ws, srow, shalf);
        __syncthreads();
        mfma_slab(Xs, Ws, wm, wn, lane, acc);
        __syncthreads();
    }

    epilogue_store(acc, bias, out, e0, N_EDGES_C, wm, wn, lane);
}

// ---------------------------------------------------------------------------
extern "C" void kernel_launch(void* const* d_in, const int* in_sizes, int n_in,
                              void* d_out, int out_size, void* d_ws, size_t ws_size,
                              hipStream_t stream)
{
    const float* nfeats    = (const float*)d_in[0];
    const float* efeats    = (const float*)d_in[1];
    const int*   u         = (const int*)d_in[2];
    const int*   v         = (const int*)d_in[3];
    const float* W_apply_w = (const float*)d_in[4];
    const float* W_apply_b = (const float*)d_in[5];
    const float* W_edge_w  = (const float*)d_in[6];
    const float* W_edge_b  = (const float*)d_in[7];

    float* out      = (float*)d_out;
    float* h_nodes  = out;                                // [50000][128]
    float* edge_out = out + (size_t)N_NODES_C * 128;      // [800000][128]

    // --- Scratch overlays inside the edge-output region (409.6 MB) ---
    // All consumed before any edge-output write to the same rows.
    float* scratch = edge_out;
    float* h_neigh = scratch;                              // 12.8M floats
    int*   cnt     = (int*)(scratch + 12800000);           // 50000
    int*   rowst   = cnt + N_NODES_C;                      // 50001
    int*   cursor  = rowst + N_NODES_C + 1;                // 50000
    int2*  pairs   = (int2*)(cursor + N_NODES_C + 2);      // 800000 int2
    int*   bsum    = (int*)(pairs + N_EDGES_C);            // 196
    int*   boff    = bsum + 256;                           // 196

    // P: prefer d_ws (removes output overlay + head GEMM); fallback overlay.
    const size_t P_ELEMS = (size_t)N_NODES_C * 256;
    bool p_in_ws = ws_size >= P_ELEMS * sizeof(unsigned short);
    unsigned short* P = p_in_ws ? (unsigned short*)d_ws
                                : (unsigned short*)edge_out;

    zero_k<<<NBLK_NODES, 256, 0, stream>>>(cnt);
    count_k<<<N_EDGES_C / 256, 256, 0, stream>>>(v, cnt);
    scan_partial_k<<<NBLK_NODES, 256, 0, stream>>>(cnt, bsum);
    scan_block_k<<<1, 256, 0, stream>>>(bsum, boff, rowst);
    scan_scatter_k<<<NBLK_NODES, 256, 0, stream>>>(cnt, boff, rowst, cursor);
    fill_k<<<N_EDGES_C / 256, 256, 0, stream>>>(v, u, cursor, pairs);
    aggregate_k<<<N_NODES_C, 256, 0, stream>>>(pairs, rowst, nfeats, efeats, h_neigh);

    node_k<<<(N_NODES_C + 127) / 128, 256, 0, stream>>>(
        nfeats, h_neigh, W_apply_w, W_apply_b, h_nodes);

    pp_k<<<dim3((N_NODES_C + 127) / 128, 2), 256, 0, stream>>>(
        h_nodes, W_edge_w, P);

    if (p_in_ws) {
        edge_add_k<<<N_EDGES_C * 32 / 256, 256, 0, stream>>>(
            P, u, v, W_edge_b, edge_out, 0);
    } else {
        edge_add_k<<<(N_EDGES_C - EDGE_HEAD_ROWS) * 32 / 256, 256, 0, stream>>>(
            P, u, v, W_edge_b, edge_out, EDGE_HEAD_ROWS);
        edge_head_k<<<EDGE_HEAD_ROWS / 128, 256, 0, stream>>>(
            h_nodes, u, v, W_edge_w, W_edge_b, edge_out);
    }
}

// Round 9
// 415.371 us; speedup vs baseline: 1.9337x; 1.0806x over previous
//
#include <hip/hip_runtime.h>
#include <hip/hip_bf16.h>

#define N_NODES_C 50000
#define N_EDGES_C 800000
#define NBLK_NODES 196                   // ceil(50000/256)
// Fallback overlay (only if ws_size too small): P overlays edge rows
// [0,50000); edge_add covers [EDGE_HEAD_ROWS,800000), edge_head the rest.
#define EDGE_HEAD_ROWS 50048             // 391 * 128

typedef __attribute__((ext_vector_type(8))) short bf16x8;
typedef __attribute__((ext_vector_type(4))) float f32x4;

__device__ __forceinline__ unsigned short f2bf(float f) {
    unsigned int x = __float_as_uint(f);
    unsigned int r = x + 0x7fffu + ((x >> 16) & 1u);   // RNE
    return (unsigned short)(r >> 16);
}
__device__ __forceinline__ float bf2f(unsigned short s) {
    return __uint_as_float(((unsigned int)s) << 16);
}

// ---------------------------------------------------------------------------
__global__ __launch_bounds__(256) void zero_k(int* __restrict__ cnt)
{
    int i = blockIdx.x * 256 + threadIdx.x;
    if (i < N_NODES_C) cnt[i] = 0;
}

__global__ __launch_bounds__(256) void count_k(const int* __restrict__ v, int* __restrict__ cnt)
{
    int e = blockIdx.x * 256 + threadIdx.x;
    atomicAdd(&cnt[v[e]], 1);
}

// ---------------------------------------------------------------------------
// Parallel scan: partial block sums -> 1-block scan of 196 -> scatter.
// ---------------------------------------------------------------------------
__global__ __launch_bounds__(256) void scan_partial_k(
    const int* __restrict__ cnt, int* __restrict__ bsum)
{
    __shared__ int ws[4];
    int b = blockIdx.x, t = threadIdx.x, lane = t & 63, wid = t >> 6;
    int i = b * 256 + t;
    int x = (i < N_NODES_C) ? cnt[i] : 0;
    int s = x;
#pragma unroll
    for (int d = 1; d < 64; d <<= 1) {
        int tv = __shfl_up(s, d, 64);
        if (lane >= d) s += tv;
    }
    if (lane == 63) ws[wid] = s;
    __syncthreads();
    if (t == 0) bsum[b] = ws[0] + ws[1] + ws[2] + ws[3];
}

__global__ __launch_bounds__(256) void scan_block_k(
    const int* __restrict__ bsum, int* __restrict__ boff, int* __restrict__ rowst)
{
    __shared__ int ws[4];
    int t = threadIdx.x, lane = t & 63, wid = t >> 6;
    int x = (t < NBLK_NODES) ? bsum[t] : 0;
    int s = x;
#pragma unroll
    for (int d = 1; d < 64; d <<= 1) {
        int tv = __shfl_up(s, d, 64);
        if (lane >= d) s += tv;
    }
    if (lane == 63) ws[wid] = s;
    __syncthreads();
    if (t == 0) {
        int a = 0;
#pragma unroll
        for (int w = 0; w < 4; ++w) { int tmp = ws[w]; ws[w] = a; a += tmp; }
    }
    __syncthreads();
    int excl = ws[wid] + s - x;
    if (t < NBLK_NODES) boff[t] = excl;
    if (t == 255) rowst[N_NODES_C] = excl;
}

__global__ __launch_bounds__(256) void scan_scatter_k(
    const int* __restrict__ cnt, const int* __restrict__ boff,
    int* __restrict__ rowst, int* __restrict__ cursor)
{
    __shared__ int ws[4];
    int b = blockIdx.x, t = threadIdx.x, lane = t & 63, wid = t >> 6;
    int i = b * 256 + t;
    int x = (i < N_NODES_C) ? cnt[i] : 0;
    int s = x;
#pragma unroll
    for (int d = 1; d < 64; d <<= 1) {
        int tv = __shfl_up(s, d, 64);
        if (lane >= d) s += tv;
    }
    if (lane == 63) ws[wid] = s;
    __syncthreads();
    if (t == 0) {
        int a = 0;
#pragma unroll
        for (int w = 0; w < 4; ++w) { int tmp = ws[w]; ws[w] = a; a += tmp; }
    }
    __syncthreads();
    int excl = boff[b] + ws[wid] + s - x;
    if (i < N_NODES_C) { rowst[i] = excl; cursor[i] = excl; }
}

__global__ __launch_bounds__(256) void fill_k(const int* __restrict__ v,
                                              const int* __restrict__ u,
                                              int* __restrict__ cursor,
                                              int2* __restrict__ pairs)
{
    int e = blockIdx.x * 256 + threadIdx.x;
    int pos = atomicAdd(&cursor[v[e]], 1);
    pairs[pos] = make_int2(e, u[e]);
}

// ---------------------------------------------------------------------------
// Aggregate: ONE WAVE per dst node (64 lanes x float4 = 256 dims), unroll-4
// (16 independent gather chains per block), no LDS epilogue. Output bf16
// (same rounding point node_k's stager applied before -> no accuracy change).
// ---------------------------------------------------------------------------
__global__ __launch_bounds__(256) void aggregate_k(
    const int2* __restrict__ pairs, const int* __restrict__ rowst,
    const float* __restrict__ nfeats, const float* __restrict__ efeats,
    unsigned short* __restrict__ hnb)
{
    int wv   = blockIdx.x * 4 + (threadIdx.x >> 6);
    int lane = threadIdx.x & 63;
    if (wv >= N_NODES_C) return;
    int s = rowst[wv], e_end = rowst[wv + 1];
    int deg = e_end - s;

    float4 a0 = make_float4(0.f, 0.f, 0.f, 0.f);
    float4 a1 = a0, a2 = a0, a3 = a0;
    int i = s;
    for (; i + 3 < e_end; i += 4) {
        int2 p0 = pairs[i + 0];
        int2 p1 = pairs[i + 1];
        int2 p2 = pairs[i + 2];
        int2 p3 = pairs[i + 3];
        const float* s0 = (lane < 32) ? (nfeats + (size_t)p0.y * 128 + lane * 4)
                                      : (efeats + (size_t)p0.x * 128 + (lane - 32) * 4);
        const float* s1 = (lane < 32) ? (nfeats + (size_t)p1.y * 128 + lane * 4)
                                      : (efeats + (size_t)p1.x * 128 + (lane - 32) * 4);
        const float* s2 = (lane < 32) ? (nfeats + (size_t)p2.y * 128 + lane * 4)
                                      : (efeats + (size_t)p2.x * 128 + (lane - 32) * 4);
        const float* s3 = (lane < 32) ? (nfeats + (size_t)p3.y * 128 + lane * 4)
                                      : (efeats + (size_t)p3.x * 128 + (lane - 32) * 4);
        float4 v0 = *reinterpret_cast<const float4*>(s0);
        float4 v1 = *reinterpret_cast<const float4*>(s1);
        float4 v2 = *reinterpret_cast<const float4*>(s2);
        float4 v3 = *reinterpret_cast<const float4*>(s3);
        a0.x += v0.x; a0.y += v0.y; a0.z += v0.z; a0.w += v0.w;
        a1.x += v1.x; a1.y += v1.y; a1.z += v1.z; a1.w += v1.w;
        a2.x += v2.x; a2.y += v2.y; a2.z += v2.z; a2.w += v2.w;
        a3.x += v3.x; a3.y += v3.y; a3.z += v3.z; a3.w += v3.w;
    }
    for (; i < e_end; ++i) {
        int2 p = pairs[i];
        const float* src = (lane < 32) ? (nfeats + (size_t)p.y * 128 + lane * 4)
                                       : (efeats + (size_t)p.x * 128 + (lane - 32) * 4);
        float4 vv = *reinterpret_cast<const float4*>(src);
        a0.x += vv.x; a0.y += vv.y; a0.z += vv.z; a0.w += vv.w;
    }
    a0.x += a1.x + a2.x + a3.x;
    a0.y += a1.y + a2.y + a3.y;
    a0.z += a1.z + a2.z + a3.z;
    a0.w += a1.w + a2.w + a3.w;
    float r = (deg > 0) ? 1.f / (float)deg : 0.f;
    ushort4 o;
    o.x = f2bf(a0.x * r); o.y = f2bf(a0.y * r);
    o.z = f2bf(a0.z * r); o.w = f2bf(a0.w * r);
    *reinterpret_cast<ushort4*>(hnb + (size_t)wv * 256 + lane * 4) = o;
}

// ---------------------------------------------------------------------------
// bf16-MFMA tile machinery (LDS [128][64] bf16, byte ^= (row&7)<<4).
// stage_half_row: fp32 source (converts). stage_half_row_cp: bf16 source.
// ---------------------------------------------------------------------------
__device__ __forceinline__ void stage_half_row(
    const float* __restrict__ src, char* __restrict__ lds, int row, int halfg)
{
#pragma unroll
    for (int g = 0; g < 4; ++g) {
        float4 f0 = reinterpret_cast<const float4*>(src)[g * 2 + 0];
        float4 f1 = reinterpret_cast<const float4*>(src)[g * 2 + 1];
        union { unsigned short s[8]; uint4 q; } pk;
        pk.s[0] = f2bf(f0.x); pk.s[1] = f2bf(f0.y);
        pk.s[2] = f2bf(f0.z); pk.s[3] = f2bf(f0.w);
        pk.s[4] = f2bf(f1.x); pk.s[5] = f2bf(f1.y);
        pk.s[6] = f2bf(f1.z); pk.s[7] = f2bf(f1.w);
        int byteoff = ((halfg * 4 + g) * 16) ^ ((row & 7) << 4);
        *reinterpret_cast<uint4*>(lds + row * 128 + byteoff) = pk.q;
    }
}

__device__ __forceinline__ void stage_half_row_cp(
    const unsigned short* __restrict__ src, char* __restrict__ lds, int row, int halfg)
{
#pragma unroll
    for (int g = 0; g < 4; ++g) {
        uint4 q = reinterpret_cast<const uint4*>(src)[g];
        int byteoff = ((halfg * 4 + g) * 16) ^ ((row & 7) << 4);
        *reinterpret_cast<uint4*>(lds + row * 128 + byteoff) = q;
    }
}

__device__ __forceinline__ void mfma_slab(
    const char* __restrict__ Xs, const char* __restrict__ Ws,
    int wm, int wn, int lane, f32x4 (&acc)[4][4])
{
#pragma unroll
    for (int c = 0; c < 2; ++c) {
        int kb = c * 64 + (lane >> 4) * 16;
        bf16x8 a[4], b[4];
#pragma unroll
        for (int i = 0; i < 4; ++i) {
            int row = wm * 64 + i * 16 + (lane & 15);
            a[i] = *reinterpret_cast<const bf16x8*>(
                Xs + row * 128 + (kb ^ ((row & 7) << 4)));
        }
#pragma unroll
        for (int j = 0; j < 4; ++j) {
            int row = wn * 64 + j * 16 + (lane & 15);
            b[j] = *reinterpret_cast<const bf16x8*>(
                Ws + row * 128 + (kb ^ ((row & 7) << 4)));
        }
#pragma unroll
        for (int i = 0; i < 4; ++i)
#pragma unroll
            for (int j = 0; j < 4; ++j)
                acc[i][j] = __builtin_amdgcn_mfma_f32_16x16x32_bf16(
                    a[i], b[j], acc[i][j], 0, 0, 0);
    }
}

__device__ __forceinline__ void epilogue_store(
    const f32x4 (&acc)[4][4], const float* __restrict__ bias,
    float* __restrict__ out, int row_base, int row_limit, int wm, int wn, int lane)
{
    int col0 = wn * 64 + (lane & 15);
    int row0 = row_base + wm * 64 + (lane >> 4) * 4;
#pragma unroll
    for (int j = 0; j < 4; ++j) {
        float bj = bias[col0 + j * 16];
#pragma unroll
        for (int i = 0; i < 4; ++i) {
#pragma unroll
            for (int r = 0; r < 4; ++r) {
                int row = row0 + i * 16 + r;
                if (row < row_limit) {
                    float val = fmaxf(acc[i][j][r] + bj, 0.f);
                    out[(size_t)row * 128 + col0 + j * 16] = val;
                }
            }
        }
    }
}

// ---------------------------------------------------------------------------
// prep_w_k: W_apply (49152) + W_edge (32768) fp32 -> bf16 tables.
// ---------------------------------------------------------------------------
__global__ __launch_bounds__(256) void prep_w_k(
    const float* __restrict__ Wa, const float* __restrict__ We,
    unsigned short* __restrict__ wa, unsigned short* __restrict__ we)
{
    int i = blockIdx.x * 256 + threadIdx.x;   // 320 blocks -> 81920
    if (i < 49152)      wa[i] = f2bf(Wa[i]);
    else if (i < 81920) we[i - 49152] = f2bf(We[i - 49152]);
}

// ---------------------------------------------------------------------------
// node_k: bf16 MFMA, K=384. X: nfeats (fp32, convert) + hnb (bf16, copy).
// W: bf16 table, copy.
// ---------------------------------------------------------------------------
__global__ __launch_bounds__(256) void node_k(
    const float* __restrict__ nfeats, const unsigned short* __restrict__ hnb,
    const unsigned short* __restrict__ wa, const float* __restrict__ bias,
    float* __restrict__ out)
{
    __shared__ uint4 XsBuf[1024];
    __shared__ uint4 WsBuf[1024];
    char* Xs = (char*)XsBuf;
    char* Ws = (char*)WsBuf;

    int tid = threadIdx.x;
    int n0  = blockIdx.x * 128;
    int wave = tid >> 6, lane = tid & 63;
    int wm = wave >> 1, wn = wave & 1;
    int srow = tid >> 1, shalf = tid & 1;

    int nrow = n0 + srow;
    if (nrow >= N_NODES_C) nrow = N_NODES_C - 1;

    f32x4 acc[4][4];
#pragma unroll
    for (int i = 0; i < 4; ++i)
#pragma unroll
        for (int j = 0; j < 4; ++j) acc[i][j] = (f32x4)0.f;

#pragma unroll
    for (int k0 = 0; k0 < 384; k0 += 64) {
        if (k0 < 128)
            stage_half_row(nfeats + (size_t)nrow * 128 + k0 + shalf * 32,
                           Xs, srow, shalf);
        else
            stage_half_row_cp(hnb + (size_t)nrow * 256 + (k0 - 128) + shalf * 32,
                              Xs, srow, shalf);
        stage_half_row_cp(wa + (size_t)srow * 384 + k0 + shalf * 32,
                          Ws, srow, shalf);
        __syncthreads();
        mfma_slab(Xs, Ws, wm, wn, lane, acc);
        __syncthreads();
    }

    epilogue_store(acc, bias, out, n0, N_NODES_C, wm, wn, lane);
}

// ---------------------------------------------------------------------------
// pp_k: P = [h @ W1^T | h @ W2^T] bf16. X: h fp32 (convert); W: bf16 copy.
// ---------------------------------------------------------------------------
__global__ __launch_bounds__(256) void pp_k(
    const float* __restrict__ h, const unsigned short* __restrict__ we,
    unsigned short* __restrict__ P)
{
    __shared__ uint4 XsBuf[1024];
    __shared__ uint4 WsBuf[1024];
    char* Xs = (char*)XsBuf;
    char* Ws = (char*)WsBuf;

    int tid = threadIdx.x;
    int n0  = blockIdx.x * 128;
    int cb  = blockIdx.y;
    int wave = tid >> 6, lane = tid & 63;
    int wm = wave >> 1, wn = wave & 1;
    int srow = tid >> 1, shalf = tid & 1;

    int nrow = n0 + srow;
    if (nrow >= N_NODES_C) nrow = N_NODES_C - 1;

    f32x4 acc[4][4];
#pragma unroll
    for (int i = 0; i < 4; ++i)
#pragma unroll
        for (int j = 0; j < 4; ++j) acc[i][j] = (f32x4)0.f;

#pragma unroll
    for (int k0 = 0; k0 < 128; k0 += 64) {
        stage_half_row(h + (size_t)nrow * 128 + k0 + shalf * 32, Xs, srow, shalf);
        stage_half_row_cp(we + (size_t)srow * 256 + cb * 128 + k0 + shalf * 32,
                          Ws, srow, shalf);
        __syncthreads();
        mfma_slab(Xs, Ws, wm, wn, lane, acc);
        __syncthreads();
    }

    int col0 = wn * 64 + (lane & 15);
    int row0 = n0 + wm * 64 + (lane >> 4) * 4;
#pragma unroll
    for (int j = 0; j < 4; ++j) {
#pragma unroll
        for (int i = 0; i < 4; ++i) {
#pragma unroll
            for (int r = 0; r < 4; ++r) {
                int row = row0 + i * 16 + r;
                if (row < N_NODES_C)
                    P[(size_t)row * 256 + cb * 128 + col0 + j * 16] = f2bf(acc[i][j][r]);
            }
        }
    }
}

// ---------------------------------------------------------------------------
// edge_add_k: out[e] = relu(P1[u[e]] + P2[v[e]] + b), e in [e_base, 800000).
// ---------------------------------------------------------------------------
__global__ __launch_bounds__(256) void edge_add_k(
    const unsigned short* __restrict__ P, const int* __restrict__ u,
    const int* __restrict__ v, const float* __restrict__ bias,
    float* __restrict__ out, int e_base)
{
    int c = blockIdx.x * 256 + threadIdx.x;
    int e = e_base + (c >> 5);
    int q = c & 31;
    int uu = u[e], vv = v[e];
    ushort4 pa = *reinterpret_cast<const ushort4*>(P + (size_t)uu * 256 + q * 4);
    ushort4 pb = *reinterpret_cast<const ushort4*>(P + (size_t)vv * 256 + 128 + q * 4);
    float4 b4 = *reinterpret_cast<const float4*>(bias + q * 4);
    float4 o;
    o.x = fmaxf(bf2f(pa.x) + bf2f(pb.x) + b4.x, 0.f);
    o.y = fmaxf(bf2f(pa.y) + bf2f(pb.y) + b4.y, 0.f);
    o.z = fmaxf(bf2f(pa.z) + bf2f(pb.z) + b4.z, 0.f);
    o.w = fmaxf(bf2f(pa.w) + bf2f(pb.w) + b4.w, 0.f);
    *reinterpret_cast<float4*>(out + (size_t)e * 128 + q * 4) = o;
}

// ---------------------------------------------------------------------------
// edge_head_k: direct bf16-MFMA GEMM for rows [0, EDGE_HEAD_ROWS) —
// FALLBACK path only (P overlaid on output; runs last). fp32 sources.
// ---------------------------------------------------------------------------
__global__ __launch_bounds__(256) void edge_head_k(
    const float* __restrict__ h, const int* __restrict__ u,
    const int* __restrict__ v, const float* __restrict__ W,
    const float* __restrict__ bias, float* __restrict__ out)
{
    __shared__ uint4 XsBuf[1024];
    __shared__ uint4 WsBuf[1024];
    __shared__ int us[128], vs[128];
    char* Xs = (char*)XsBuf;
    char* Ws = (char*)WsBuf;

    int tid = threadIdx.x;
    int e0  = blockIdx.x * 128;
    if (tid < 128) us[tid]       = u[e0 + tid];
    else           vs[tid - 128] = v[e0 + tid - 128];
    __syncthreads();

    int wave = tid >> 6, lane = tid & 63;
    int wm = wave >> 1, wn = wave & 1;
    int srow = tid >> 1, shalf = tid & 1;

    f32x4 acc[4][4];
#pragma unroll
    for (int i = 0; i < 4; ++i)
#pragma unroll
        for (int j = 0; j < 4; ++j) acc[i][j] = (f32x4)0.f;

#pragma unroll
    for (int k0 = 0; k0 < 256; k0 += 64) {
        int node = (k0 < 128) ? us[srow] : vs[srow];
        stage_half_row(h + (size_t)node * 128 + (k0 & 127) + shalf * 32,
                       Xs, srow, shalf);
        stage_half_row(W + (size_t)srow * 256 + k0 + shalf * 32,
                       Ws, srow, shalf);
        __syncthreads();
        mfma_slab(Xs, Ws, wm, wn, lane, acc);
        __syncthreads();
    }

    epilogue_store(acc, bias, out, e0, N_EDGES_C, wm, wn, lane);
}

// ---------------------------------------------------------------------------
extern "C" void kernel_launch(void* const* d_in, const int* in_sizes, int n_in,
                              void* d_out, int out_size, void* d_ws, size_t ws_size,
                              hipStream_t stream)
{
    const float* nfeats    = (const float*)d_in[0];
    const float* efeats    = (const float*)d_in[1];
    const int*   u         = (const int*)d_in[2];
    const int*   v         = (const int*)d_in[3];
    const float* W_apply_w = (const float*)d_in[4];
    const float* W_apply_b = (const float*)d_in[5];
    const float* W_edge_w  = (const float*)d_in[6];
    const float* W_edge_b  = (const float*)d_in[7];

    float* out      = (float*)d_out;
    float* h_nodes  = out;                                // [50000][128]
    float* edge_out = out + (size_t)N_NODES_C * 128;      // [800000][128]

    // --- Scratch overlays inside the edge-output region (409.6 MB) ---
    // hnb (bf16 h_neigh, 25.6 MB) sits at the base; in the fallback path the
    // SAME region later holds P (identical footprint, disjoint lifetime:
    // hnb dead after node_k, P written by pp_k after node_k).
    unsigned short* hnb = (unsigned short*)edge_out;       // [50000][256] bf16
    int*   cnt     = (int*)(edge_out + 6400000);           // 50000
    int*   rowst   = cnt + N_NODES_C;                      // 50001
    int*   cursor  = rowst + N_NODES_C + 1;                // 50000
    int2*  pairs   = (int2*)(cursor + N_NODES_C + 2);      // 800000 int2
    int*   bsum    = (int*)(pairs + N_EDGES_C);            // 196
    int*   boff    = bsum + 256;                           // 196
    unsigned short* wa = (unsigned short*)(boff + 256);    // 49152 bf16
    unsigned short* we = wa + 49152;                       // 32768 bf16
    // (tables read only by node_k/pp_k, which complete before any edge-row
    //  write reaches this region in either path)

    const size_t P_ELEMS = (size_t)N_NODES_C * 256;
    bool p_in_ws = ws_size >= P_ELEMS * sizeof(unsigned short);
    unsigned short* P = p_in_ws ? (unsigned short*)d_ws
                                : (unsigned short*)edge_out;

    zero_k<<<NBLK_NODES, 256, 0, stream>>>(cnt);
    prep_w_k<<<320, 256, 0, stream>>>(W_apply_w, W_edge_w, wa, we);
    count_k<<<N_EDGES_C / 256, 256, 0, stream>>>(v, cnt);
    scan_partial_k<<<NBLK_NODES, 256, 0, stream>>>(cnt, bsum);
    scan_block_k<<<1, 256, 0, stream>>>(bsum, boff, rowst);
    scan_scatter_k<<<NBLK_NODES, 256, 0, stream>>>(cnt, boff, rowst, cursor);
    fill_k<<<N_EDGES_C / 256, 256, 0, stream>>>(v, u, cursor, pairs);
    aggregate_k<<<N_NODES_C / 4, 256, 0, stream>>>(pairs, rowst, nfeats, efeats, hnb);

    node_k<<<(N_NODES_C + 127) / 128, 256, 0, stream>>>(
        nfeats, hnb, wa, W_apply_b, h_nodes);

    pp_k<<<dim3((N_NODES_C + 127) / 128, 2), 256, 0, stream>>>(
        h_nodes, we, P);

    if (p_in_ws) {
        edge_add_k<<<N_EDGES_C * 32 / 256, 256, 0, stream>>>(
            P, u, v, W_edge_b, edge_out, 0);
    } else {
        edge_add_k<<<(N_EDGES_C - EDGE_HEAD_ROWS) * 32 / 256, 256, 0, stream>>>(
            P, u, v, W_edge_b, edge_out, EDGE_HEAD_ROWS);
        edge_head_k<<<EDGE_HEAD_ROWS / 128, 256, 0, stream>>>(
            h_nodes, u, v, W_edge_w, W_edge_b, edge_out);
    }
}

// Round 10
// 409.167 us; speedup vs baseline: 1.9630x; 1.0152x over previous
//
#include <hip/hip_runtime.h>
#include <hip/hip_bf16.h>

#define N_NODES_C 50000
#define N_EDGES_C 800000
#define NBLK_NODES 196                   // ceil(50000/256)
// Fallback overlay (only if ws_size too small): P overlays edge rows
// [0,50000); edge_add covers [EDGE_HEAD_ROWS,800000), edge_head the rest.
#define EDGE_HEAD_ROWS 50048             // 391 * 128

typedef __attribute__((ext_vector_type(8))) short bf16x8;
typedef __attribute__((ext_vector_type(4))) float f32x4;

__device__ __forceinline__ unsigned short f2bf(float f) {
    unsigned int x = __float_as_uint(f);
    unsigned int r = x + 0x7fffu + ((x >> 16) & 1u);   // RNE
    return (unsigned short)(r >> 16);
}
__device__ __forceinline__ float bf2f(unsigned short s) {
    return __uint_as_float(((unsigned int)s) << 16);
}

// ---------------------------------------------------------------------------
// setup_k: zero cnt + convert both weight tables to bf16 (one launch).
// blocks [0,196): cnt; [196,388): wa (49152); [388,516): we (32768).
// ---------------------------------------------------------------------------
__global__ __launch_bounds__(256) void setup_k(
    const float* __restrict__ Wa, const float* __restrict__ We,
    unsigned short* __restrict__ wa, unsigned short* __restrict__ we,
    int* __restrict__ cnt)
{
    int b = blockIdx.x, t = threadIdx.x;
    if (b < 196) {
        int i = b * 256 + t;
        if (i < N_NODES_C) cnt[i] = 0;
    } else if (b < 388) {
        int i = (b - 196) * 256 + t;
        wa[i] = f2bf(Wa[i]);
    } else {
        int i = (b - 388) * 256 + t;
        we[i] = f2bf(We[i]);
    }
}

__global__ __launch_bounds__(256) void count_k(const int* __restrict__ v, int* __restrict__ cnt)
{
    int e = blockIdx.x * 256 + threadIdx.x;
    atomicAdd(&cnt[v[e]], 1);
}

// ---------------------------------------------------------------------------
// Parallel scan: partial block sums -> 1-block scan of 196 -> scatter.
// ---------------------------------------------------------------------------
__global__ __launch_bounds__(256) void scan_partial_k(
    const int* __restrict__ cnt, int* __restrict__ bsum)
{
    __shared__ int ws[4];
    int b = blockIdx.x, t = threadIdx.x, lane = t & 63, wid = t >> 6;
    int i = b * 256 + t;
    int x = (i < N_NODES_C) ? cnt[i] : 0;
    int s = x;
#pragma unroll
    for (int d = 1; d < 64; d <<= 1) {
        int tv = __shfl_up(s, d, 64);
        if (lane >= d) s += tv;
    }
    if (lane == 63) ws[wid] = s;
    __syncthreads();
    if (t == 0) bsum[b] = ws[0] + ws[1] + ws[2] + ws[3];
}

__global__ __launch_bounds__(256) void scan_block_k(
    const int* __restrict__ bsum, int* __restrict__ boff, int* __restrict__ rowst)
{
    __shared__ int ws[4];
    int t = threadIdx.x, lane = t & 63, wid = t >> 6;
    int x = (t < NBLK_NODES) ? bsum[t] : 0;
    int s = x;
#pragma unroll
    for (int d = 1; d < 64; d <<= 1) {
        int tv = __shfl_up(s, d, 64);
        if (lane >= d) s += tv;
    }
    if (lane == 63) ws[wid] = s;
    __syncthreads();
    if (t == 0) {
        int a = 0;
#pragma unroll
        for (int w = 0; w < 4; ++w) { int tmp = ws[w]; ws[w] = a; a += tmp; }
    }
    __syncthreads();
    int excl = ws[wid] + s - x;
    if (t < NBLK_NODES) boff[t] = excl;
    if (t == 255) rowst[N_NODES_C] = excl;
}

__global__ __launch_bounds__(256) void scan_scatter_k(
    const int* __restrict__ cnt, const int* __restrict__ boff,
    int* __restrict__ rowst, int* __restrict__ cursor)
{
    __shared__ int ws[4];
    int b = blockIdx.x, t = threadIdx.x, lane = t & 63, wid = t >> 6;
    int i = b * 256 + t;
    int x = (i < N_NODES_C) ? cnt[i] : 0;
    int s = x;
#pragma unroll
    for (int d = 1; d < 64; d <<= 1) {
        int tv = __shfl_up(s, d, 64);
        if (lane >= d) s += tv;
    }
    if (lane == 63) ws[wid] = s;
    __syncthreads();
    if (t == 0) {
        int a = 0;
#pragma unroll
        for (int w = 0; w < 4; ++w) { int tmp = ws[w]; ws[w] = a; a += tmp; }
    }
    __syncthreads();
    int excl = boff[b] + ws[wid] + s - x;
    if (i < N_NODES_C) { rowst[i] = excl; cursor[i] = excl; }
}

__global__ __launch_bounds__(256) void fill_k(const int* __restrict__ v,
                                              const int* __restrict__ u,
                                              int* __restrict__ cursor,
                                              int2* __restrict__ pairs)
{
    int e = blockIdx.x * 256 + threadIdx.x;
    int pos = atomicAdd(&cursor[v[e]], 1);
    pairs[pos] = make_int2(e, u[e]);
}

// ---------------------------------------------------------------------------
// Aggregate: one wave per dst node, predicated unroll-8 (all 8 pairs loads,
// then all 8 gathers issued before any predicate) -> 8 chains in flight.
// ---------------------------------------------------------------------------
__global__ __launch_bounds__(256) void aggregate_k(
    const int2* __restrict__ pairs, const int* __restrict__ rowst,
    const float* __restrict__ nfeats, const float* __restrict__ efeats,
    unsigned short* __restrict__ hnb)
{
    int wv   = blockIdx.x * 4 + (threadIdx.x >> 6);
    int lane = threadIdx.x & 63;
    if (wv >= N_NODES_C) return;
    int s = rowst[wv], e_end = rowst[wv + 1];
    int deg = e_end - s;

    if (deg == 0) {   // guard: clamped index below would read pairs[s-1]
        *reinterpret_cast<ushort4*>(hnb + (size_t)wv * 256 + lane * 4) =
            make_ushort4(0, 0, 0, 0);
        return;
    }

    float4 a0 = make_float4(0.f, 0.f, 0.f, 0.f);
    float4 a1 = a0, a2 = a0, a3 = a0;
    for (int base = s; base < e_end; base += 8) {
        int2 p[8];
#pragma unroll
        for (int t = 0; t < 8; ++t) {
            int idx = base + t;
            p[t] = pairs[idx < e_end ? idx : e_end - 1];
        }
        float4 val[8];
#pragma unroll
        for (int t = 0; t < 8; ++t) {
            const float* src = (lane < 32)
                ? (nfeats + (size_t)p[t].y * 128 + lane * 4)
                : (efeats + (size_t)p[t].x * 128 + (lane - 32) * 4);
            val[t] = *reinterpret_cast<const float4*>(src);
        }
#pragma unroll
        for (int t = 0; t < 8; ++t) {
            if (base + t < e_end) {
                float4* a = (t & 2) ? ((t & 1) ? &a3 : &a2)
                                    : ((t & 1) ? &a1 : &a0);
                a->x += val[t].x; a->y += val[t].y;
                a->z += val[t].z; a->w += val[t].w;
            }
        }
    }
    a0.x += a1.x + a2.x + a3.x;
    a0.y += a1.y + a2.y + a3.y;
    a0.z += a1.z + a2.z + a3.z;
    a0.w += a1.w + a2.w + a3.w;
    float r = 1.f / (float)deg;
    ushort4 o;
    o.x = f2bf(a0.x * r); o.y = f2bf(a0.y * r);
    o.z = f2bf(a0.z * r); o.w = f2bf(a0.w * r);
    *reinterpret_cast<ushort4*>(hnb + (size_t)wv * 256 + lane * 4) = o;
}

// ---------------------------------------------------------------------------
// bf16-MFMA tile machinery (LDS [128][64] bf16, byte ^= (row&7)<<4).
// ---------------------------------------------------------------------------
__device__ __forceinline__ void stage_half_row(
    const float* __restrict__ src, char* __restrict__ lds, int row, int halfg)
{
#pragma unroll
    for (int g = 0; g < 4; ++g) {
        float4 f0 = reinterpret_cast<const float4*>(src)[g * 2 + 0];
        float4 f1 = reinterpret_cast<const float4*>(src)[g * 2 + 1];
        union { unsigned short s[8]; uint4 q; } pk;
        pk.s[0] = f2bf(f0.x); pk.s[1] = f2bf(f0.y);
        pk.s[2] = f2bf(f0.z); pk.s[3] = f2bf(f0.w);
        pk.s[4] = f2bf(f1.x); pk.s[5] = f2bf(f1.y);
        pk.s[6] = f2bf(f1.z); pk.s[7] = f2bf(f1.w);
        int byteoff = ((halfg * 4 + g) * 16) ^ ((row & 7) << 4);
        *reinterpret_cast<uint4*>(lds + row * 128 + byteoff) = pk.q;
    }
}

__device__ __forceinline__ void stage_half_row_cp(
    const unsigned short* __restrict__ src, char* __restrict__ lds, int row, int halfg)
{
#pragma unroll
    for (int g = 0; g < 4; ++g) {
        uint4 q = reinterpret_cast<const uint4*>(src)[g];
        int byteoff = ((halfg * 4 + g) * 16) ^ ((row & 7) << 4);
        *reinterpret_cast<uint4*>(lds + row * 128 + byteoff) = q;
    }
}

__device__ __forceinline__ void mfma_slab(
    const char* __restrict__ Xs, const char* __restrict__ Ws,
    int wm, int wn, int lane, f32x4 (&acc)[4][4])
{
#pragma unroll
    for (int c = 0; c < 2; ++c) {
        int kb = c * 64 + (lane >> 4) * 16;
        bf16x8 a[4], b[4];
#pragma unroll
        for (int i = 0; i < 4; ++i) {
            int row = wm * 64 + i * 16 + (lane & 15);
            a[i] = *reinterpret_cast<const bf16x8*>(
                Xs + row * 128 + (kb ^ ((row & 7) << 4)));
        }
#pragma unroll
        for (int j = 0; j < 4; ++j) {
            int row = wn * 64 + j * 16 + (lane & 15);
            b[j] = *reinterpret_cast<const bf16x8*>(
                Ws + row * 128 + (kb ^ ((row & 7) << 4)));
        }
#pragma unroll
        for (int i = 0; i < 4; ++i)
#pragma unroll
            for (int j = 0; j < 4; ++j)
                acc[i][j] = __builtin_amdgcn_mfma_f32_16x16x32_bf16(
                    a[i], b[j], acc[i][j], 0, 0, 0);
    }
}

__device__ __forceinline__ void epilogue_store(
    const f32x4 (&acc)[4][4], const float* __restrict__ bias,
    float* __restrict__ out, int row_base, int row_limit, int wm, int wn, int lane)
{
    int col0 = wn * 64 + (lane & 15);
    int row0 = row_base + wm * 64 + (lane >> 4) * 4;
#pragma unroll
    for (int j = 0; j < 4; ++j) {
        float bj = bias[col0 + j * 16];
#pragma unroll
        for (int i = 0; i < 4; ++i) {
#pragma unroll
            for (int r = 0; r < 4; ++r) {
                int row = row0 + i * 16 + r;
                if (row < row_limit) {
                    float val = fmaxf(acc[i][j][r] + bj, 0.f);
                    out[(size_t)row * 128 + col0 + j * 16] = val;
                }
            }
        }
    }
}

// ---------------------------------------------------------------------------
// node_k (fused): phase 1 = h = relu(concat(nfeats,hnb) @ Wa^T + b), K=384.
// phase 2 = P = [h @ W1^T | h @ W2^T] bf16, reading this block's own h rows
// back from global (L2-hot; ordered by the post-epilogue __syncthreads).
// Fallback aliasing safe: P rows n0..n0+127 overwrite only this block's
// already-consumed hnb rows.
// ---------------------------------------------------------------------------
__global__ __launch_bounds__(256) void node_k(
    const float* __restrict__ nfeats, const unsigned short* __restrict__ hnb,
    const unsigned short* __restrict__ wa, const unsigned short* __restrict__ we,
    const float* __restrict__ bias, float* __restrict__ out,
    unsigned short* __restrict__ P)
{
    __shared__ uint4 XsBuf[1024];
    __shared__ uint4 WsBuf[1024];
    char* Xs = (char*)XsBuf;
    char* Ws = (char*)WsBuf;

    int tid = threadIdx.x;
    int n0  = blockIdx.x * 128;
    int wave = tid >> 6, lane = tid & 63;
    int wm = wave >> 1, wn = wave & 1;
    int srow = tid >> 1, shalf = tid & 1;

    int nrow = n0 + srow;
    if (nrow >= N_NODES_C) nrow = N_NODES_C - 1;

    f32x4 acc[4][4];
#pragma unroll
    for (int i = 0; i < 4; ++i)
#pragma unroll
        for (int j = 0; j < 4; ++j) acc[i][j] = (f32x4)0.f;

#pragma unroll
    for (int k0 = 0; k0 < 384; k0 += 64) {
        if (k0 < 128)
            stage_half_row(nfeats + (size_t)nrow * 128 + k0 + shalf * 32,
                           Xs, srow, shalf);
        else
            stage_half_row_cp(hnb + (size_t)nrow * 256 + (k0 - 128) + shalf * 32,
                              Xs, srow, shalf);
        stage_half_row_cp(wa + (size_t)srow * 384 + k0 + shalf * 32,
                          Ws, srow, shalf);
        __syncthreads();
        mfma_slab(Xs, Ws, wm, wn, lane, acc);
        __syncthreads();
    }

    epilogue_store(acc, bias, out, n0, N_NODES_C, wm, wn, lane);
    __syncthreads();   // h rows of this block visible block-wide

    // ---- phase 2: P for rows n0..n0+127 ----
    int col0 = wn * 64 + (lane & 15);
    int row0 = n0 + wm * 64 + (lane >> 4) * 4;
#pragma unroll
    for (int cb = 0; cb < 2; ++cb) {
        f32x4 accP[4][4];
#pragma unroll
        for (int i = 0; i < 4; ++i)
#pragma unroll
            for (int j = 0; j < 4; ++j) accP[i][j] = (f32x4)0.f;

#pragma unroll
        for (int s2 = 0; s2 < 2; ++s2) {
            int k0 = s2 * 64;
            stage_half_row(out + (size_t)nrow * 128 + k0 + shalf * 32,
                           Xs, srow, shalf);
            stage_half_row_cp(we + (size_t)srow * 256 + cb * 128 + k0 + shalf * 32,
                              Ws, srow, shalf);
            __syncthreads();
            mfma_slab(Xs, Ws, wm, wn, lane, accP);
            __syncthreads();
        }

#pragma unroll
        for (int j = 0; j < 4; ++j) {
#pragma unroll
            for (int i = 0; i < 4; ++i) {
#pragma unroll
                for (int r = 0; r < 4; ++r) {
                    int row = row0 + i * 16 + r;
                    if (row < N_NODES_C)
                        P[(size_t)row * 256 + cb * 128 + col0 + j * 16] =
                            f2bf(accP[i][j][r]);
                }
            }
        }
    }
}

// ---------------------------------------------------------------------------
// edge_add_k: out[e] = relu(P1[u[e]] + P2[v[e]] + b), e in [e_base, 800000).
// ---------------------------------------------------------------------------
__global__ __launch_bounds__(256) void edge_add_k(
    const unsigned short* __restrict__ P, const int* __restrict__ u,
    const int* __restrict__ v, const float* __restrict__ bias,
    float* __restrict__ out, int e_base)
{
    int c = blockIdx.x * 256 + threadIdx.x;
    int e = e_base + (c >> 5);
    int q = c & 31;
    int uu = u[e], vv = v[e];
    ushort4 pa = *reinterpret_cast<const ushort4*>(P + (size_t)uu * 256 + q * 4);
    ushort4 pb = *reinterpret_cast<const ushort4*>(P + (size_t)vv * 256 + 128 + q * 4);
    float4 b4 = *reinterpret_cast<const float4*>(bias + q * 4);
    float4 o;
    o.x = fmaxf(bf2f(pa.x) + bf2f(pb.x) + b4.x, 0.f);
    o.y = fmaxf(bf2f(pa.y) + bf2f(pb.y) + b4.y, 0.f);
    o.z = fmaxf(bf2f(pa.z) + bf2f(pb.z) + b4.z, 0.f);
    o.w = fmaxf(bf2f(pa.w) + bf2f(pb.w) + b4.w, 0.f);
    *reinterpret_cast<float4*>(out + (size_t)e * 128 + q * 4) = o;
}

// ---------------------------------------------------------------------------
// edge_head_k: direct bf16-MFMA GEMM for rows [0, EDGE_HEAD_ROWS) —
// FALLBACK path only (P overlaid on output; runs last). fp32 sources.
// ---------------------------------------------------------------------------
__global__ __launch_bounds__(256) void edge_head_k(
    const float* __restrict__ h, const int* __restrict__ u,
    const int* __restrict__ v, const float* __restrict__ W,
    const float* __restrict__ bias, float* __restrict__ out)
{
    __shared__ uint4 XsBuf[1024];
    __shared__ uint4 WsBuf[1024];
    __shared__ int us[128], vs[128];
    char* Xs = (char*)XsBuf;
    char* Ws = (char*)WsBuf;

    int tid = threadIdx.x;
    int e0  = blockIdx.x * 128;
    if (tid < 128) us[tid]       = u[e0 + tid];
    else           vs[tid - 128] = v[e0 + tid - 128];
    __syncthreads();

    int wave = tid >> 6, lane = tid & 63;
    int wm = wave >> 1, wn = wave & 1;
    int srow = tid >> 1, shalf = tid & 1;

    f32x4 acc[4][4];
#pragma unroll
    for (int i = 0; i < 4; ++i)
#pragma unroll
        for (int j = 0; j < 4; ++j) acc[i][j] = (f32x4)0.f;

#pragma unroll
    for (int k0 = 0; k0 < 256; k0 += 64) {
        int node = (k0 < 128) ? us[srow] : vs[srow];
        stage_half_row(h + (size_t)node * 128 + (k0 & 127) + shalf * 32,
                       Xs, srow, shalf);
        stage_half_row(W + (size_t)srow * 256 + k0 + shalf * 32,
                       Ws, srow, shalf);
        __syncthreads();
        mfma_slab(Xs, Ws, wm, wn, lane, acc);
        __syncthreads();
    }

    epilogue_store(acc, bias, out, e0, N_EDGES_C, wm, wn, lane);
}

// ---------------------------------------------------------------------------
extern "C" void kernel_launch(void* const* d_in, const int* in_sizes, int n_in,
                              void* d_out, int out_size, void* d_ws, size_t ws_size,
                              hipStream_t stream)
{
    const float* nfeats    = (const float*)d_in[0];
    const float* efeats    = (const float*)d_in[1];
    const int*   u         = (const int*)d_in[2];
    const int*   v         = (const int*)d_in[3];
    const float* W_apply_w = (const float*)d_in[4];
    const float* W_apply_b = (const float*)d_in[5];
    const float* W_edge_w  = (const float*)d_in[6];
    const float* W_edge_b  = (const float*)d_in[7];

    float* out      = (float*)d_out;
    float* h_nodes  = out;                                // [50000][128]
    float* edge_out = out + (size_t)N_NODES_C * 128;      // [800000][128]

    // --- Scratch overlays inside the edge-output region (409.6 MB) ---
    // hnb (bf16 h_neigh) at base; in the fallback path the same region later
    // holds P (identical footprint; per-block disjoint lifetime — see node_k).
    unsigned short* hnb = (unsigned short*)edge_out;       // [50000][256] bf16
    int*   cnt     = (int*)(edge_out + 6400000);           // 50000
    int*   rowst   = cnt + N_NODES_C;                      // 50001
    int*   cursor  = rowst + N_NODES_C + 1;                // 50000
    int2*  pairs   = (int2*)(cursor + N_NODES_C + 2);      // 800000 int2
    int*   bsum    = (int*)(pairs + N_EDGES_C);            // 196
    int*   boff    = bsum + 256;                           // 196
    unsigned short* wa = (unsigned short*)(boff + 256);    // 49152 bf16
    unsigned short* we = wa + 49152;                       // 32768 bf16

    const size_t P_ELEMS = (size_t)N_NODES_C * 256;
    bool p_in_ws = ws_size >= P_ELEMS * sizeof(unsigned short);
    unsigned short* P = p_in_ws ? (unsigned short*)d_ws
                                : (unsigned short*)edge_out;

    setup_k<<<516, 256, 0, stream>>>(W_apply_w, W_edge_w, wa, we, cnt);
    count_k<<<N_EDGES_C / 256, 256, 0, stream>>>(v, cnt);
    scan_partial_k<<<NBLK_NODES, 256, 0, stream>>>(cnt, bsum);
    scan_block_k<<<1, 256, 0, stream>>>(bsum, boff, rowst);
    scan_scatter_k<<<NBLK_NODES, 256, 0, stream>>>(cnt, boff, rowst, cursor);
    fill_k<<<N_EDGES_C / 256, 256, 0, stream>>>(v, u, cursor, pairs);
    aggregate_k<<<N_NODES_C / 4, 256, 0, stream>>>(pairs, rowst, nfeats, efeats, hnb);

    node_k<<<(N_NODES_C + 127) / 128, 256, 0, stream>>>(
        nfeats, hnb, wa, we, W_apply_b, h_nodes, P);

    if (p_in_ws) {
        edge_add_k<<<N_EDGES_C * 32 / 256, 256, 0, stream>>>(
            P, u, v, W_edge_b, edge_out, 0);
    } else {
        edge_add_k<<<(N_EDGES_C - EDGE_HEAD_ROWS) * 32 / 256, 256, 0, stream>>>(
            P, u, v, W_edge_b, edge_out, EDGE_HEAD_ROWS);
        edge_head_k<<<EDGE_HEAD_ROWS / 128, 256, 0, stream>>>(
            h_nodes, u, v, W_edge_w, W_edge_b, edge_out);
    }
}

// Round 11
// 398.199 us; speedup vs baseline: 2.0171x; 1.0275x over previous
//
#include <hip/hip_runtime.h>
#include <hip/hip_bf16.h>

#define N_NODES_C 50000
#define N_EDGES_C 800000
#define NBLK_NODES 196                   // ceil(50000/256)
// Fallback (small ws): scratch occupies edge rows [0, ~64100); CSR edge pass
// predicates writes to e >= EDGE_HEAD_ROWS; head GEMM covers the rest.
#define EDGE_HEAD_ROWS 64128             // 501 * 128

typedef __attribute__((ext_vector_type(8))) short bf16x8;
typedef __attribute__((ext_vector_type(4))) float f32x4;

__device__ __forceinline__ unsigned short f2bf(float f) {
    unsigned int x = __float_as_uint(f);
    unsigned int r = x + 0x7fffu + ((x >> 16) & 1u);   // RNE
    return (unsigned short)(r >> 16);
}
__device__ __forceinline__ float bf2f(unsigned short s) {
    return __uint_as_float(((unsigned int)s) << 16);
}

// ---------------------------------------------------------------------------
// setup_k: zero cnt + convert both weight tables to bf16 (one launch).
// ---------------------------------------------------------------------------
__global__ __launch_bounds__(256) void setup_k(
    const float* __restrict__ Wa, const float* __restrict__ We,
    unsigned short* __restrict__ wa, unsigned short* __restrict__ we,
    int* __restrict__ cnt)
{
    int b = blockIdx.x, t = threadIdx.x;
    if (b < 196) {
        int i = b * 256 + t;
        if (i < N_NODES_C) cnt[i] = 0;
    } else if (b < 388) {
        int i = (b - 196) * 256 + t;
        wa[i] = f2bf(Wa[i]);
    } else {
        int i = (b - 388) * 256 + t;
        we[i] = f2bf(We[i]);
    }
}

__global__ __launch_bounds__(256) void count_k(const int* __restrict__ v, int* __restrict__ cnt)
{
    int e = blockIdx.x * 256 + threadIdx.x;
    atomicAdd(&cnt[v[e]], 1);
}

// ---------------------------------------------------------------------------
// Parallel scan: partial block sums -> 1-block scan of 196 -> scatter.
// ---------------------------------------------------------------------------
__global__ __launch_bounds__(256) void scan_partial_k(
    const int* __restrict__ cnt, int* __restrict__ bsum)
{
    __shared__ int ws[4];
    int b = blockIdx.x, t = threadIdx.x, lane = t & 63, wid = t >> 6;
    int i = b * 256 + t;
    int x = (i < N_NODES_C) ? cnt[i] : 0;
    int s = x;
#pragma unroll
    for (int d = 1; d < 64; d <<= 1) {
        int tv = __shfl_up(s, d, 64);
        if (lane >= d) s += tv;
    }
    if (lane == 63) ws[wid] = s;
    __syncthreads();
    if (t == 0) bsum[b] = ws[0] + ws[1] + ws[2] + ws[3];
}

__global__ __launch_bounds__(256) void scan_block_k(
    const int* __restrict__ bsum, int* __restrict__ boff, int* __restrict__ rowst)
{
    __shared__ int ws[4];
    int t = threadIdx.x, lane = t & 63, wid = t >> 6;
    int x = (t < NBLK_NODES) ? bsum[t] : 0;
    int s = x;
#pragma unroll
    for (int d = 1; d < 64; d <<= 1) {
        int tv = __shfl_up(s, d, 64);
        if (lane >= d) s += tv;
    }
    if (lane == 63) ws[wid] = s;
    __syncthreads();
    if (t == 0) {
        int a = 0;
#pragma unroll
        for (int w = 0; w < 4; ++w) { int tmp = ws[w]; ws[w] = a; a += tmp; }
    }
    __syncthreads();
    int excl = ws[wid] + s - x;
    if (t < NBLK_NODES) boff[t] = excl;
    if (t == 255) rowst[N_NODES_C] = excl;
}

__global__ __launch_bounds__(256) void scan_scatter_k(
    const int* __restrict__ cnt, const int* __restrict__ boff,
    int* __restrict__ rowst, int* __restrict__ cursor)
{
    __shared__ int ws[4];
    int b = blockIdx.x, t = threadIdx.x, lane = t & 63, wid = t >> 6;
    int i = b * 256 + t;
    int x = (i < N_NODES_C) ? cnt[i] : 0;
    int s = x;
#pragma unroll
    for (int d = 1; d < 64; d <<= 1) {
        int tv = __shfl_up(s, d, 64);
        if (lane >= d) s += tv;
    }
    if (lane == 63) ws[wid] = s;
    __syncthreads();
    if (t == 0) {
        int a = 0;
#pragma unroll
        for (int w = 0; w < 4; ++w) { int tmp = ws[w]; ws[w] = a; a += tmp; }
    }
    __syncthreads();
    int excl = boff[b] + ws[wid] + s - x;
    if (i < N_NODES_C) { rowst[i] = excl; cursor[i] = excl; }
}

__global__ __launch_bounds__(256) void fill_k(const int* __restrict__ v,
                                              const int* __restrict__ u,
                                              int* __restrict__ cursor,
                                              int2* __restrict__ pairs)
{
    int e = blockIdx.x * 256 + threadIdx.x;
    int pos = atomicAdd(&cursor[v[e]], 1);
    pairs[pos] = make_int2(e, u[e]);
}

// ---------------------------------------------------------------------------
// Aggregate: one wave per dst node, predicated unroll-8.
// ---------------------------------------------------------------------------
__global__ __launch_bounds__(256) void aggregate_k(
    const int2* __restrict__ pairs, const int* __restrict__ rowst,
    const float* __restrict__ nfeats, const float* __restrict__ efeats,
    unsigned short* __restrict__ hnb)
{
    int wv   = blockIdx.x * 4 + (threadIdx.x >> 6);
    int lane = threadIdx.x & 63;
    if (wv >= N_NODES_C) return;
    int s = rowst[wv], e_end = rowst[wv + 1];
    int deg = e_end - s;

    if (deg == 0) {
        *reinterpret_cast<ushort4*>(hnb + (size_t)wv * 256 + lane * 4) =
            make_ushort4(0, 0, 0, 0);
        return;
    }

    float4 a0 = make_float4(0.f, 0.f, 0.f, 0.f);
    float4 a1 = a0, a2 = a0, a3 = a0;
    for (int base = s; base < e_end; base += 8) {
        int2 p[8];
#pragma unroll
        for (int t = 0; t < 8; ++t) {
            int idx = base + t;
            p[t] = pairs[idx < e_end ? idx : e_end - 1];
        }
        float4 val[8];
#pragma unroll
        for (int t = 0; t < 8; ++t) {
            const float* src = (lane < 32)
                ? (nfeats + (size_t)p[t].y * 128 + lane * 4)
                : (efeats + (size_t)p[t].x * 128 + (lane - 32) * 4);
            val[t] = *reinterpret_cast<const float4*>(src);
        }
#pragma unroll
        for (int t = 0; t < 8; ++t) {
            if (base + t < e_end) {
                float4* a = (t & 2) ? ((t & 1) ? &a3 : &a2)
                                    : ((t & 1) ? &a1 : &a0);
                a->x += val[t].x; a->y += val[t].y;
                a->z += val[t].z; a->w += val[t].w;
            }
        }
    }
    a0.x += a1.x + a2.x + a3.x;
    a0.y += a1.y + a2.y + a3.y;
    a0.z += a1.z + a2.z + a3.z;
    a0.w += a1.w + a2.w + a3.w;
    float r = 1.f / (float)deg;
    ushort4 o;
    o.x = f2bf(a0.x * r); o.y = f2bf(a0.y * r);
    o.z = f2bf(a0.z * r); o.w = f2bf(a0.w * r);
    *reinterpret_cast<ushort4*>(hnb + (size_t)wv * 256 + lane * 4) = o;
}

// ---------------------------------------------------------------------------
// bf16-MFMA tile machinery (LDS [128][64] bf16, byte ^= (row&7)<<4).
// ---------------------------------------------------------------------------
__device__ __forceinline__ void stage_half_row(
    const float* __restrict__ src, char* __restrict__ lds, int row, int halfg)
{
#pragma unroll
    for (int g = 0; g < 4; ++g) {
        float4 f0 = reinterpret_cast<const float4*>(src)[g * 2 + 0];
        float4 f1 = reinterpret_cast<const float4*>(src)[g * 2 + 1];
        union { unsigned short s[8]; uint4 q; } pk;
        pk.s[0] = f2bf(f0.x); pk.s[1] = f2bf(f0.y);
        pk.s[2] = f2bf(f0.z); pk.s[3] = f2bf(f0.w);
        pk.s[4] = f2bf(f1.x); pk.s[5] = f2bf(f1.y);
        pk.s[6] = f2bf(f1.z); pk.s[7] = f2bf(f1.w);
        int byteoff = ((halfg * 4 + g) * 16) ^ ((row & 7) << 4);
        *reinterpret_cast<uint4*>(lds + row * 128 + byteoff) = pk.q;
    }
}

__device__ __forceinline__ void stage_half_row_cp(
    const unsigned short* __restrict__ src, char* __restrict__ lds, int row, int halfg)
{
#pragma unroll
    for (int g = 0; g < 4; ++g) {
        uint4 q = reinterpret_cast<const uint4*>(src)[g];
        int byteoff = ((halfg * 4 + g) * 16) ^ ((row & 7) << 4);
        *reinterpret_cast<uint4*>(lds + row * 128 + byteoff) = q;
    }
}

__device__ __forceinline__ void mfma_slab(
    const char* __restrict__ Xs, const char* __restrict__ Ws,
    int wm, int wn, int lane, f32x4 (&acc)[4][4])
{
#pragma unroll
    for (int c = 0; c < 2; ++c) {
        int kb = c * 64 + (lane >> 4) * 16;
        bf16x8 a[4], b[4];
#pragma unroll
        for (int i = 0; i < 4; ++i) {
            int row = wm * 64 + i * 16 + (lane & 15);
            a[i] = *reinterpret_cast<const bf16x8*>(
                Xs + row * 128 + (kb ^ ((row & 7) << 4)));
        }
#pragma unroll
        for (int j = 0; j < 4; ++j) {
            int row = wn * 64 + j * 16 + (lane & 15);
            b[j] = *reinterpret_cast<const bf16x8*>(
                Ws + row * 128 + (kb ^ ((row & 7) << 4)));
        }
#pragma unroll
        for (int i = 0; i < 4; ++i)
#pragma unroll
            for (int j = 0; j < 4; ++j)
                acc[i][j] = __builtin_amdgcn_mfma_f32_16x16x32_bf16(
                    a[i], b[j], acc[i][j], 0, 0, 0);
    }
}

__device__ __forceinline__ void epilogue_store(
    const f32x4 (&acc)[4][4], const float* __restrict__ bias,
    float* __restrict__ out, int row_base, int row_limit, int wm, int wn, int lane)
{
    int col0 = wn * 64 + (lane & 15);
    int row0 = row_base + wm * 64 + (lane >> 4) * 4;
#pragma unroll
    for (int j = 0; j < 4; ++j) {
        float bj = bias[col0 + j * 16];
#pragma unroll
        for (int i = 0; i < 4; ++i) {
#pragma unroll
            for (int r = 0; r < 4; ++r) {
                int row = row0 + i * 16 + r;
                if (row < row_limit) {
                    float val = fmaxf(acc[i][j][r] + bj, 0.f);
                    out[(size_t)row * 128 + col0 + j * 16] = val;
                }
            }
        }
    }
}

// ---------------------------------------------------------------------------
// node_k (fused): phase 1 = h (K=384); phase 2 = P bf16 (reads own h rows,
// L2-hot). Per-block row ownership makes fallback P-over-hnb overlay safe.
// ---------------------------------------------------------------------------
__global__ __launch_bounds__(256) void node_k(
    const float* __restrict__ nfeats, const unsigned short* __restrict__ hnb,
    const unsigned short* __restrict__ wa, const unsigned short* __restrict__ we,
    const float* __restrict__ bias, float* __restrict__ out,
    unsigned short* __restrict__ P)
{
    __shared__ uint4 XsBuf[1024];
    __shared__ uint4 WsBuf[1024];
    char* Xs = (char*)XsBuf;
    char* Ws = (char*)WsBuf;

    int tid = threadIdx.x;
    int n0  = blockIdx.x * 128;
    int wave = tid >> 6, lane = tid & 63;
    int wm = wave >> 1, wn = wave & 1;
    int srow = tid >> 1, shalf = tid & 1;

    int nrow = n0 + srow;
    if (nrow >= N_NODES_C) nrow = N_NODES_C - 1;

    f32x4 acc[4][4];
#pragma unroll
    for (int i = 0; i < 4; ++i)
#pragma unroll
        for (int j = 0; j < 4; ++j) acc[i][j] = (f32x4)0.f;

#pragma unroll
    for (int k0 = 0; k0 < 384; k0 += 64) {
        if (k0 < 128)
            stage_half_row(nfeats + (size_t)nrow * 128 + k0 + shalf * 32,
                           Xs, srow, shalf);
        else
            stage_half_row_cp(hnb + (size_t)nrow * 256 + (k0 - 128) + shalf * 32,
                              Xs, srow, shalf);
        stage_half_row_cp(wa + (size_t)srow * 384 + k0 + shalf * 32,
                          Ws, srow, shalf);
        __syncthreads();
        mfma_slab(Xs, Ws, wm, wn, lane, acc);
        __syncthreads();
    }

    epilogue_store(acc, bias, out, n0, N_NODES_C, wm, wn, lane);
    __syncthreads();

    // ---- phase 2: P for rows n0..n0+127 ----
    int col0 = wn * 64 + (lane & 15);
    int row0 = n0 + wm * 64 + (lane >> 4) * 4;
#pragma unroll
    for (int cb = 0; cb < 2; ++cb) {
        f32x4 accP[4][4];
#pragma unroll
        for (int i = 0; i < 4; ++i)
#pragma unroll
            for (int j = 0; j < 4; ++j) accP[i][j] = (f32x4)0.f;

#pragma unroll
        for (int s2 = 0; s2 < 2; ++s2) {
            int k0 = s2 * 64;
            stage_half_row(out + (size_t)nrow * 128 + k0 + shalf * 32,
                           Xs, srow, shalf);
            stage_half_row_cp(we + (size_t)srow * 256 + cb * 128 + k0 + shalf * 32,
                              Ws, srow, shalf);
            __syncthreads();
            mfma_slab(Xs, Ws, wm, wn, lane, accP);
            __syncthreads();
        }

#pragma unroll
        for (int j = 0; j < 4; ++j) {
#pragma unroll
            for (int i = 0; i < 4; ++i) {
#pragma unroll
                for (int r = 0; r < 4; ++r) {
                    int row = row0 + i * 16 + r;
                    if (row < N_NODES_C)
                        P[(size_t)row * 256 + cb * 128 + col0 + j * 16] =
                            f2bf(accP[i][j][r]);
                }
            }
        }
    }
}

// ---------------------------------------------------------------------------
// edge_csr_k: CSR-ordered edge epilogue. One wave per dst node; P2[v]+bias
// cached in registers once per node; per edge gather only P1[u] (256B) and
// write out[e] (512B). Unroll-4 per 32-lane half. Writes predicated to
// e >= e_min (fallback keeps scratch rows for the head GEMM).
// ---------------------------------------------------------------------------
__global__ __launch_bounds__(256) void edge_csr_k(
    const int2* __restrict__ pairs, const int* __restrict__ rowst,
    const unsigned short* __restrict__ P, const float* __restrict__ bias,
    float* __restrict__ out, int e_min)
{
    int wv   = blockIdx.x * 4 + (threadIdx.x >> 6);
    int lane = threadIdx.x & 63;
    int l32  = lane & 31, half = lane >> 5;
    if (wv >= N_NODES_C) return;
    int s = rowst[wv], e_end = rowst[wv + 1];
    if (s + half >= e_end) return;

    ushort4 q2 = *reinterpret_cast<const ushort4*>(P + (size_t)wv * 256 + 128 + l32 * 4);
    float4  b4 = *reinterpret_cast<const float4*>(bias + l32 * 4);
    float t2x = bf2f(q2.x) + b4.x;
    float t2y = bf2f(q2.y) + b4.y;
    float t2z = bf2f(q2.z) + b4.z;
    float t2w = bf2f(q2.w) + b4.w;

    for (int base = s + half; base < e_end; base += 8) {
        int2 pr[4];
#pragma unroll
        for (int t = 0; t < 4; ++t) {
            int idx = base + t * 2;
            pr[t] = pairs[idx < e_end ? idx : e_end - 1];
        }
        ushort4 p1[4];
#pragma unroll
        for (int t = 0; t < 4; ++t)
            p1[t] = *reinterpret_cast<const ushort4*>(
                P + (size_t)pr[t].y * 256 + l32 * 4);
#pragma unroll
        for (int t = 0; t < 4; ++t) {
            int idx = base + t * 2;
            if (idx < e_end && pr[t].x >= e_min) {
                float4 o;
                o.x = fmaxf(bf2f(p1[t].x) + t2x, 0.f);
                o.y = fmaxf(bf2f(p1[t].y) + t2y, 0.f);
                o.z = fmaxf(bf2f(p1[t].z) + t2z, 0.f);
                o.w = fmaxf(bf2f(p1[t].w) + t2w, 0.f);
                *reinterpret_cast<float4*>(
                    out + (size_t)pr[t].x * 128 + l32 * 4) = o;
            }
        }
    }
}

// ---------------------------------------------------------------------------
// edge_head_k: direct bf16-MFMA GEMM for rows [0, EDGE_HEAD_ROWS) —
// FALLBACK path only. fp32 sources; runs last.
// ---------------------------------------------------------------------------
__global__ __launch_bounds__(256) void edge_head_k(
    const float* __restrict__ h, const int* __restrict__ u,
    const int* __restrict__ v, const float* __restrict__ W,
    const float* __restrict__ bias, float* __restrict__ out)
{
    __shared__ uint4 XsBuf[1024];
    __shared__ uint4 WsBuf[1024];
    __shared__ int us[128], vs[128];
    char* Xs = (char*)XsBuf;
    char* Ws = (char*)WsBuf;

    int tid = threadIdx.x;
    int e0  = blockIdx.x * 128;
    if (tid < 128) us[tid]       = u[e0 + tid];
    else           vs[tid - 128] = v[e0 + tid - 128];
    __syncthreads();

    int wave = tid >> 6, lane = tid & 63;
    int wm = wave >> 1, wn = wave & 1;
    int srow = tid >> 1, shalf = tid & 1;

    f32x4 acc[4][4];
#pragma unroll
    for (int i = 0; i < 4; ++i)
#pragma unroll
        for (int j = 0; j < 4; ++j) acc[i][j] = (f32x4)0.f;

#pragma unroll
    for (int k0 = 0; k0 < 256; k0 += 64) {
        int node = (k0 < 128) ? us[srow] : vs[srow];
        stage_half_row(h + (size_t)node * 128 + (k0 & 127) + shalf * 32,
                       Xs, srow, shalf);
        stage_half_row(W + (size_t)srow * 256 + k0 + shalf * 32,
                       Ws, srow, shalf);
        __syncthreads();
        mfma_slab(Xs, Ws, wm, wn, lane, acc);
        __syncthreads();
    }

    epilogue_store(acc, bias, out, e0, N_EDGES_C, wm, wn, lane);
}

// ---------------------------------------------------------------------------
extern "C" void kernel_launch(void* const* d_in, const int* in_sizes, int n_in,
                              void* d_out, int out_size, void* d_ws, size_t ws_size,
                              hipStream_t stream)
{
    const float* nfeats    = (const float*)d_in[0];
    const float* efeats    = (const float*)d_in[1];
    const int*   u         = (const int*)d_in[2];
    const int*   v         = (const int*)d_in[3];
    const float* W_apply_w = (const float*)d_in[4];
    const float* W_apply_b = (const float*)d_in[5];
    const float* W_edge_w  = (const float*)d_in[6];
    const float* W_edge_b  = (const float*)d_in[7];

    float* out      = (float*)d_out;
    float* h_nodes  = out;                                // [50000][128]
    float* edge_out = out + (size_t)N_NODES_C * 128;      // [800000][128]

    // Overlay scratch (edge-output region): all dead before the first edge-
    // row write that could touch it (ws path) or protected by e_min +
    // head GEMM (fallback).
    unsigned short* hnb = (unsigned short*)edge_out;       // [50000][256] bf16
    int*   cnt     = (int*)(edge_out + 6400000);           // 50000
    int*   cursor  = cnt + N_NODES_C;                      // 50000
    int*   bsum    = cursor + N_NODES_C;                   // 196 (+pad)
    int*   boff    = bsum + 256;                           // 196 (+pad)
    unsigned short* wa = (unsigned short*)(boff + 256);    // 49152 bf16
    unsigned short* we = wa + 49152;                       // 32768 bf16
    // Fallback locations for P / pairs / rowst (inside overlay):
    unsigned short* P_fb     = (unsigned short*)edge_out;  // over hnb (node_k)
    int2*           pairs_fb = (int2*)(we + 32768);        // 800000 int2
    int*            rowst_fb = (int*)(pairs_fb + N_EDGES_C); // 50001

    // WS layout (preferred): P + pairs + rowst must survive into edge_csr_k.
    const size_t WS_NEED = (size_t)N_NODES_C * 256 * 2     // P 25.6 MB
                         + (size_t)N_EDGES_C * 8           // pairs 6.4 MB
                         + (size_t)(N_NODES_C + 1) * 4;    // rowst
    bool use_ws = ws_size >= WS_NEED;
    unsigned short* P     = use_ws ? (unsigned short*)d_ws : P_fb;
    int2*           pairs = use_ws ? (int2*)((char*)d_ws + (size_t)N_NODES_C * 512)
                                   : pairs_fb;
    int*            rowst = use_ws ? (int*)(pairs + N_EDGES_C) : rowst_fb;

    setup_k<<<516, 256, 0, stream>>>(W_apply_w, W_edge_w, wa, we, cnt);
    count_k<<<N_EDGES_C / 256, 256, 0, stream>>>(v, cnt);
    scan_partial_k<<<NBLK_NODES, 256, 0, stream>>>(cnt, bsum);
    scan_block_k<<<1, 256, 0, stream>>>(bsum, boff, rowst);
    scan_scatter_k<<<NBLK_NODES, 256, 0, stream>>>(cnt, boff, rowst, cursor);
    fill_k<<<N_EDGES_C / 256, 256, 0, stream>>>(v, u, cursor, pairs);
    aggregate_k<<<N_NODES_C / 4, 256, 0, stream>>>(pairs, rowst, nfeats, efeats, hnb);

    node_k<<<(N_NODES_C + 127) / 128, 256, 0, stream>>>(
        nfeats, hnb, wa, we, W_apply_b, h_nodes, P);

    if (use_ws) {
        edge_csr_k<<<N_NODES_C / 4, 256, 0, stream>>>(
            pairs, rowst, P, W_edge_b, edge_out, 0);
    } else {
        edge_csr_k<<<N_NODES_C / 4, 256, 0, stream>>>(
            pairs, rowst, P, W_edge_b, edge_out, EDGE_HEAD_ROWS);
        edge_head_k<<<EDGE_HEAD_ROWS / 128, 256, 0, stream>>>(
            h_nodes, u, v, W_edge_w, W_edge_b, edge_out);
    }
}

// Round 12
// 397.676 us; speedup vs baseline: 2.0197x; 1.0013x over previous
//
#include <hip/hip_runtime.h>
#include <hip/hip_bf16.h>

#define N_NODES_C 50000
#define N_EDGES_C 800000
#define NBLK_NODES 196                   // ceil(50000/256)
// Fallback (small ws): scratch occupies edge rows [0, ~64100); CSR edge pass
// predicates writes to e >= EDGE_HEAD_ROWS; head GEMM covers the rest.
#define EDGE_HEAD_ROWS 64128             // 501 * 128

typedef __attribute__((ext_vector_type(8))) short bf16x8;
typedef __attribute__((ext_vector_type(4))) float f32x4;

__device__ __forceinline__ unsigned short f2bf(float f) {
    unsigned int x = __float_as_uint(f);
    unsigned int r = x + 0x7fffu + ((x >> 16) & 1u);   // RNE
    return (unsigned short)(r >> 16);
}
__device__ __forceinline__ float bf2f(unsigned short s) {
    return __uint_as_float(((unsigned int)s) << 16);
}

// ---------------------------------------------------------------------------
// setup_k: zero cnt + convert both weight tables to bf16 (one launch).
// ---------------------------------------------------------------------------
__global__ __launch_bounds__(256) void setup_k(
    const float* __restrict__ Wa, const float* __restrict__ We,
    unsigned short* __restrict__ wa, unsigned short* __restrict__ we,
    int* __restrict__ cnt)
{
    int b = blockIdx.x, t = threadIdx.x;
    if (b < 196) {
        int i = b * 256 + t;
        if (i < N_NODES_C) cnt[i] = 0;
    } else if (b < 388) {
        int i = (b - 196) * 256 + t;
        wa[i] = f2bf(Wa[i]);
    } else {
        int i = (b - 388) * 256 + t;
        we[i] = f2bf(We[i]);
    }
}

__global__ __launch_bounds__(256) void count_k(const int* __restrict__ v, int* __restrict__ cnt)
{
    int e = blockIdx.x * 256 + threadIdx.x;
    atomicAdd(&cnt[v[e]], 1);
}

// ---------------------------------------------------------------------------
// Parallel scan: partial block sums -> scatter (block-prefix computed inline).
// ---------------------------------------------------------------------------
__global__ __launch_bounds__(256) void scan_partial_k(
    const int* __restrict__ cnt, int* __restrict__ bsum)
{
    __shared__ int ws[4];
    int b = blockIdx.x, t = threadIdx.x, lane = t & 63, wid = t >> 6;
    int i = b * 256 + t;
    int x = (i < N_NODES_C) ? cnt[i] : 0;
    int s = x;
#pragma unroll
    for (int d = 1; d < 64; d <<= 1) {
        int tv = __shfl_up(s, d, 64);
        if (lane >= d) s += tv;
    }
    if (lane == 63) ws[wid] = s;
    __syncthreads();
    if (t == 0) bsum[b] = ws[0] + ws[1] + ws[2] + ws[3];
}

// scan_scatter_k: computes this block's global prefix from bsum inline
// (sum of bsum[j], j<b), then the per-element exclusive scan. Block 195
// also writes rowst[N_NODES_C] = total.
__global__ __launch_bounds__(256) void scan_scatter_k(
    const int* __restrict__ cnt, const int* __restrict__ bsum,
    int* __restrict__ rowst, int* __restrict__ cursor)
{
    __shared__ int ws[4];
    __shared__ int bpref, btot;
    int b = blockIdx.x, t = threadIdx.x, lane = t & 63, wid = t >> 6;

    // ---- block prefix: sum bsum[0..b) (and total for the last block) ----
    {
        int mine = (t < NBLK_NODES && t < b) ? bsum[t] : 0;
        int tot  = (t < NBLK_NODES) ? bsum[t] : 0;
        int sp = mine, st = tot;
#pragma unroll
        for (int d = 1; d < 64; d <<= 1) {
            sp += __shfl_xor(sp, d, 64);
            st += __shfl_xor(st, d, 64);
        }
        if (lane == 0) { ws[wid] = sp; }
        __syncthreads();
        if (t == 0) bpref = ws[0] + ws[1] + ws[2] + ws[3];
        __syncthreads();
        if (b == NBLK_NODES - 1) {
            if (lane == 0) ws[wid] = st;
            __syncthreads();
            if (t == 0) btot = ws[0] + ws[1] + ws[2] + ws[3];
            __syncthreads();
            if (t == 0) rowst[N_NODES_C] = btot;
        }
        __syncthreads();
    }

    // ---- per-element exclusive scan within the block ----
    int i = b * 256 + t;
    int x = (i < N_NODES_C) ? cnt[i] : 0;
    int s = x;
#pragma unroll
    for (int d = 1; d < 64; d <<= 1) {
        int tv = __shfl_up(s, d, 64);
        if (lane >= d) s += tv;
    }
    if (lane == 63) ws[wid] = s;
    __syncthreads();
    if (t == 0) {
        int a = 0;
#pragma unroll
        for (int w = 0; w < 4; ++w) { int tmp = ws[w]; ws[w] = a; a += tmp; }
    }
    __syncthreads();
    int excl = bpref + ws[wid] + s - x;
    if (i < N_NODES_C) { rowst[i] = excl; cursor[i] = excl; }
}

__global__ __launch_bounds__(256) void fill_k(const int* __restrict__ v,
                                              const int* __restrict__ u,
                                              int* __restrict__ cursor,
                                              int2* __restrict__ pairs)
{
    int e = blockIdx.x * 256 + threadIdx.x;
    int pos = atomicAdd(&cursor[v[e]], 1);
    pairs[pos] = make_int2(e, u[e]);
}

// ---------------------------------------------------------------------------
// Aggregate: one wave per dst node, predicated unroll-8 (BW-saturated per
// R9 A/B; left unchanged).
// ---------------------------------------------------------------------------
__global__ __launch_bounds__(256) void aggregate_k(
    const int2* __restrict__ pairs, const int* __restrict__ rowst,
    const float* __restrict__ nfeats, const float* __restrict__ efeats,
    unsigned short* __restrict__ hnb)
{
    int wv   = blockIdx.x * 4 + (threadIdx.x >> 6);
    int lane = threadIdx.x & 63;
    if (wv >= N_NODES_C) return;
    int s = rowst[wv], e_end = rowst[wv + 1];
    int deg = e_end - s;

    if (deg == 0) {
        *reinterpret_cast<ushort4*>(hnb + (size_t)wv * 256 + lane * 4) =
            make_ushort4(0, 0, 0, 0);
        return;
    }

    float4 a0 = make_float4(0.f, 0.f, 0.f, 0.f);
    float4 a1 = a0, a2 = a0, a3 = a0;
    for (int base = s; base < e_end; base += 8) {
        int2 p[8];
#pragma unroll
        for (int t = 0; t < 8; ++t) {
            int idx = base + t;
            p[t] = pairs[idx < e_end ? idx : e_end - 1];
        }
        float4 val[8];
#pragma unroll
        for (int t = 0; t < 8; ++t) {
            const float* src = (lane < 32)
                ? (nfeats + (size_t)p[t].y * 128 + lane * 4)
                : (efeats + (size_t)p[t].x * 128 + (lane - 32) * 4);
            val[t] = *reinterpret_cast<const float4*>(src);
        }
#pragma unroll
        for (int t = 0; t < 8; ++t) {
            if (base + t < e_end) {
                float4* a = (t & 2) ? ((t & 1) ? &a3 : &a2)
                                    : ((t & 1) ? &a1 : &a0);
                a->x += val[t].x; a->y += val[t].y;
                a->z += val[t].z; a->w += val[t].w;
            }
        }
    }
    a0.x += a1.x + a2.x + a3.x;
    a0.y += a1.y + a2.y + a3.y;
    a0.z += a1.z + a2.z + a3.z;
    a0.w += a1.w + a2.w + a3.w;
    float r = 1.f / (float)deg;
    ushort4 o;
    o.x = f2bf(a0.x * r); o.y = f2bf(a0.y * r);
    o.z = f2bf(a0.z * r); o.w = f2bf(a0.w * r);
    *reinterpret_cast<ushort4*>(hnb + (size_t)wv * 256 + lane * 4) = o;
}

// ---------------------------------------------------------------------------
// bf16-MFMA tile machinery (LDS [128][64] bf16, byte ^= (row&7)<<4).
// ---------------------------------------------------------------------------
__device__ __forceinline__ void stage_half_row(
    const float* __restrict__ src, char* __restrict__ lds, int row, int halfg)
{
#pragma unroll
    for (int g = 0; g < 4; ++g) {
        float4 f0 = reinterpret_cast<const float4*>(src)[g * 2 + 0];
        float4 f1 = reinterpret_cast<const float4*>(src)[g * 2 + 1];
        union { unsigned short s[8]; uint4 q; } pk;
        pk.s[0] = f2bf(f0.x); pk.s[1] = f2bf(f0.y);
        pk.s[2] = f2bf(f0.z); pk.s[3] = f2bf(f0.w);
        pk.s[4] = f2bf(f1.x); pk.s[5] = f2bf(f1.y);
        pk.s[6] = f2bf(f1.z); pk.s[7] = f2bf(f1.w);
        int byteoff = ((halfg * 4 + g) * 16) ^ ((row & 7) << 4);
        *reinterpret_cast<uint4*>(lds + row * 128 + byteoff) = pk.q;
    }
}

__device__ __forceinline__ void stage_half_row_cp(
    const unsigned short* __restrict__ src, char* __restrict__ lds, int row, int halfg)
{
#pragma unroll
    for (int g = 0; g < 4; ++g) {
        uint4 q = reinterpret_cast<const uint4*>(src)[g];
        int byteoff = ((halfg * 4 + g) * 16) ^ ((row & 7) << 4);
        *reinterpret_cast<uint4*>(lds + row * 128 + byteoff) = q;
    }
}

__device__ __forceinline__ void mfma_slab(
    const char* __restrict__ Xs, const char* __restrict__ Ws,
    int wm, int wn, int lane, f32x4 (&acc)[4][4])
{
#pragma unroll
    for (int c = 0; c < 2; ++c) {
        int kb = c * 64 + (lane >> 4) * 16;
        bf16x8 a[4], b[4];
#pragma unroll
        for (int i = 0; i < 4; ++i) {
            int row = wm * 64 + i * 16 + (lane & 15);
            a[i] = *reinterpret_cast<const bf16x8*>(
                Xs + row * 128 + (kb ^ ((row & 7) << 4)));
        }
#pragma unroll
        for (int j = 0; j < 4; ++j) {
            int row = wn * 64 + j * 16 + (lane & 15);
            b[j] = *reinterpret_cast<const bf16x8*>(
                Ws + row * 128 + (kb ^ ((row & 7) << 4)));
        }
#pragma unroll
        for (int i = 0; i < 4; ++i)
#pragma unroll
            for (int j = 0; j < 4; ++j)
                acc[i][j] = __builtin_amdgcn_mfma_f32_16x16x32_bf16(
                    a[i], b[j], acc[i][j], 0, 0, 0);
    }
}

__device__ __forceinline__ void epilogue_store(
    const f32x4 (&acc)[4][4], const float* __restrict__ bias,
    float* __restrict__ out, int row_base, int row_limit, int wm, int wn, int lane)
{
    int col0 = wn * 64 + (lane & 15);
    int row0 = row_base + wm * 64 + (lane >> 4) * 4;
#pragma unroll
    for (int j = 0; j < 4; ++j) {
        float bj = bias[col0 + j * 16];
#pragma unroll
        for (int i = 0; i < 4; ++i) {
#pragma unroll
            for (int r = 0; r < 4; ++r) {
                int row = row0 + i * 16 + r;
                if (row < row_limit) {
                    float val = fmaxf(acc[i][j][r] + bj, 0.f);
                    out[(size_t)row * 128 + col0 + j * 16] = val;
                }
            }
        }
    }
}

// ---------------------------------------------------------------------------
// node_k (fused): phase 1 = h (K=384); phase 2 = P bf16 (reads own h rows,
// L2-hot). Per-block row ownership makes fallback P-over-hnb overlay safe.
// ---------------------------------------------------------------------------
__global__ __launch_bounds__(256) void node_k(
    const float* __restrict__ nfeats, const unsigned short* __restrict__ hnb,
    const unsigned short* __restrict__ wa, const unsigned short* __restrict__ we,
    const float* __restrict__ bias, float* __restrict__ out,
    unsigned short* __restrict__ P)
{
    __shared__ uint4 XsBuf[1024];
    __shared__ uint4 WsBuf[1024];
    char* Xs = (char*)XsBuf;
    char* Ws = (char*)WsBuf;

    int tid = threadIdx.x;
    int n0  = blockIdx.x * 128;
    int wave = tid >> 6, lane = tid & 63;
    int wm = wave >> 1, wn = wave & 1;
    int srow = tid >> 1, shalf = tid & 1;

    int nrow = n0 + srow;
    if (nrow >= N_NODES_C) nrow = N_NODES_C - 1;

    f32x4 acc[4][4];
#pragma unroll
    for (int i = 0; i < 4; ++i)
#pragma unroll
        for (int j = 0; j < 4; ++j) acc[i][j] = (f32x4)0.f;

#pragma unroll
    for (int k0 = 0; k0 < 384; k0 += 64) {
        if (k0 < 128)
            stage_half_row(nfeats + (size_t)nrow * 128 + k0 + shalf * 32,
                           Xs, srow, shalf);
        else
            stage_half_row_cp(hnb + (size_t)nrow * 256 + (k0 - 128) + shalf * 32,
                              Xs, srow, shalf);
        stage_half_row_cp(wa + (size_t)srow * 384 + k0 + shalf * 32,
                          Ws, srow, shalf);
        __syncthreads();
        mfma_slab(Xs, Ws, wm, wn, lane, acc);
        __syncthreads();
    }

    epilogue_store(acc, bias, out, n0, N_NODES_C, wm, wn, lane);
    __syncthreads();

    // ---- phase 2: P for rows n0..n0+127 ----
    int col0 = wn * 64 + (lane & 15);
    int row0 = n0 + wm * 64 + (lane >> 4) * 4;
#pragma unroll
    for (int cb = 0; cb < 2; ++cb) {
        f32x4 accP[4][4];
#pragma unroll
        for (int i = 0; i < 4; ++i)
#pragma unroll
            for (int j = 0; j < 4; ++j) accP[i][j] = (f32x4)0.f;

#pragma unroll
        for (int s2 = 0; s2 < 2; ++s2) {
            int k0 = s2 * 64;
            stage_half_row(out + (size_t)nrow * 128 + k0 + shalf * 32,
                           Xs, srow, shalf);
            stage_half_row_cp(we + (size_t)srow * 256 + cb * 128 + k0 + shalf * 32,
                              Ws, srow, shalf);
            __syncthreads();
            mfma_slab(Xs, Ws, wm, wn, lane, accP);
            __syncthreads();
        }

#pragma unroll
        for (int j = 0; j < 4; ++j) {
#pragma unroll
            for (int i = 0; i < 4; ++i) {
#pragma unroll
                for (int r = 0; r < 4; ++r) {
                    int row = row0 + i * 16 + r;
                    if (row < N_NODES_C)
                        P[(size_t)row * 256 + cb * 128 + col0 + j * 16] =
                            f2bf(accP[i][j][r]);
                }
            }
        }
    }
}

// ---------------------------------------------------------------------------
// edge_csr_k: CSR-ordered edge epilogue. One wave per dst node; P2[v]+bias
// in registers once per node; per edge gather only P1[u] + write out[e].
// Unroll-8 per 32-lane half (8 gathers in flight). Writes predicated to
// e >= e_min (fallback keeps scratch rows for the head GEMM).
// ---------------------------------------------------------------------------
__global__ __launch_bounds__(256) void edge_csr_k(
    const int2* __restrict__ pairs, const int* __restrict__ rowst,
    const unsigned short* __restrict__ P, const float* __restrict__ bias,
    float* __restrict__ out, int e_min)
{
    int wv   = blockIdx.x * 4 + (threadIdx.x >> 6);
    int lane = threadIdx.x & 63;
    int l32  = lane & 31, half = lane >> 5;
    if (wv >= N_NODES_C) return;
    int s = rowst[wv], e_end = rowst[wv + 1];
    if (s + half >= e_end) return;

    ushort4 q2 = *reinterpret_cast<const ushort4*>(P + (size_t)wv * 256 + 128 + l32 * 4);
    float4  b4 = *reinterpret_cast<const float4*>(bias + l32 * 4);
    float t2x = bf2f(q2.x) + b4.x;
    float t2y = bf2f(q2.y) + b4.y;
    float t2z = bf2f(q2.z) + b4.z;
    float t2w = bf2f(q2.w) + b4.w;

    for (int base = s + half; base < e_end; base += 16) {
        int2 pr[8];
#pragma unroll
        for (int t = 0; t < 8; ++t) {
            int idx = base + t * 2;
            pr[t] = pairs[idx < e_end ? idx : e_end - 1];
        }
        ushort4 p1[8];
#pragma unroll
        for (int t = 0; t < 8; ++t)
            p1[t] = *reinterpret_cast<const ushort4*>(
                P + (size_t)pr[t].y * 256 + l32 * 4);
#pragma unroll
        for (int t = 0; t < 8; ++t) {
            int idx = base + t * 2;
            if (idx < e_end && pr[t].x >= e_min) {
                float4 o;
                o.x = fmaxf(bf2f(p1[t].x) + t2x, 0.f);
                o.y = fmaxf(bf2f(p1[t].y) + t2y, 0.f);
                o.z = fmaxf(bf2f(p1[t].z) + t2z, 0.f);
                o.w = fmaxf(bf2f(p1[t].w) + t2w, 0.f);
                *reinterpret_cast<float4*>(
                    out + (size_t)pr[t].x * 128 + l32 * 4) = o;
            }
        }
    }
}

// ---------------------------------------------------------------------------
// edge_head_k: direct bf16-MFMA GEMM for rows [0, EDGE_HEAD_ROWS) —
// FALLBACK path only. fp32 sources; runs last.
// ---------------------------------------------------------------------------
__global__ __launch_bounds__(256) void edge_head_k(
    const float* __restrict__ h, const int* __restrict__ u,
    const int* __restrict__ v, const float* __restrict__ W,
    const float* __restrict__ bias, float* __restrict__ out)
{
    __shared__ uint4 XsBuf[1024];
    __shared__ uint4 WsBuf[1024];
    __shared__ int us[128], vs[128];
    char* Xs = (char*)XsBuf;
    char* Ws = (char*)WsBuf;

    int tid = threadIdx.x;
    int e0  = blockIdx.x * 128;
    if (tid < 128) us[tid]       = u[e0 + tid];
    else           vs[tid - 128] = v[e0 + tid - 128];
    __syncthreads();

    int wave = tid >> 6, lane = tid & 63;
    int wm = wave >> 1, wn = wave & 1;
    int srow = tid >> 1, shalf = tid & 1;

    f32x4 acc[4][4];
#pragma unroll
    for (int i = 0; i < 4; ++i)
#pragma unroll
        for (int j = 0; j < 4; ++j) acc[i][j] = (f32x4)0.f;

#pragma unroll
    for (int k0 = 0; k0 < 256; k0 += 64) {
        int node = (k0 < 128) ? us[srow] : vs[srow];
        stage_half_row(h + (size_t)node * 128 + (k0 & 127) + shalf * 32,
                       Xs, srow, shalf);
        stage_half_row(W + (size_t)srow * 256 + k0 + shalf * 32,
                       Ws, srow, shalf);
        __syncthreads();
        mfma_slab(Xs, Ws, wm, wn, lane, acc);
        __syncthreads();
    }

    epilogue_store(acc, bias, out, e0, N_EDGES_C, wm, wn, lane);
}

// ---------------------------------------------------------------------------
extern "C" void kernel_launch(void* const* d_in, const int* in_sizes, int n_in,
                              void* d_out, int out_size, void* d_ws, size_t ws_size,
                              hipStream_t stream)
{
    const float* nfeats    = (const float*)d_in[0];
    const float* efeats    = (const float*)d_in[1];
    const int*   u         = (const int*)d_in[2];
    const int*   v         = (const int*)d_in[3];
    const float* W_apply_w = (const float*)d_in[4];
    const float* W_apply_b = (const float*)d_in[5];
    const float* W_edge_w  = (const float*)d_in[6];
    const float* W_edge_b  = (const float*)d_in[7];

    float* out      = (float*)d_out;
    float* h_nodes  = out;                                // [50000][128]
    float* edge_out = out + (size_t)N_NODES_C * 128;      // [800000][128]

    // Overlay scratch (edge-output region): all dead before the first edge-
    // row write that could touch it (ws path) or protected by e_min +
    // head GEMM (fallback).
    unsigned short* hnb = (unsigned short*)edge_out;       // [50000][256] bf16
    int*   cnt     = (int*)(edge_out + 6400000);           // 50000
    int*   cursor  = cnt + N_NODES_C;                      // 50000
    int*   bsum    = cursor + N_NODES_C;                   // 196 (+pad)
    unsigned short* wa = (unsigned short*)(bsum + 256);    // 49152 bf16
    unsigned short* we = wa + 49152;                       // 32768 bf16
    // Fallback locations for P / pairs / rowst (inside overlay):
    unsigned short* P_fb     = (unsigned short*)edge_out;  // over hnb (node_k)
    int2*           pairs_fb = (int2*)(we + 32768);        // 800000 int2
    int*            rowst_fb = (int*)(pairs_fb + N_EDGES_C); // 50001

    // WS layout (preferred): P + pairs + rowst must survive into edge_csr_k.
    const size_t WS_NEED = (size_t)N_NODES_C * 256 * 2     // P 25.6 MB
                         + (size_t)N_EDGES_C * 8           // pairs 6.4 MB
                         + (size_t)(N_NODES_C + 1) * 4;    // rowst
    bool use_ws = ws_size >= WS_NEED;
    unsigned short* P     = use_ws ? (unsigned short*)d_ws : P_fb;
    int2*           pairs = use_ws ? (int2*)((char*)d_ws + (size_t)N_NODES_C * 512)
                                   : pairs_fb;
    int*            rowst = use_ws ? (int*)(pairs + N_EDGES_C) : rowst_fb;

    setup_k<<<516, 256, 0, stream>>>(W_apply_w, W_edge_w, wa, we, cnt);
    count_k<<<N_EDGES_C / 256, 256, 0, stream>>>(v, cnt);
    scan_partial_k<<<NBLK_NODES, 256, 0, stream>>>(cnt, bsum);
    scan_scatter_k<<<NBLK_NODES, 256, 0, stream>>>(cnt, bsum, rowst, cursor);
    fill_k<<<N_EDGES_C / 256, 256, 0, stream>>>(v, u, cursor, pairs);
    aggregate_k<<<N_NODES_C / 4, 256, 0, stream>>>(pairs, rowst, nfeats, efeats, hnb);

    node_k<<<(N_NODES_C + 127) / 128, 256, 0, stream>>>(
        nfeats, hnb, wa, we, W_apply_b, h_nodes, P);

    if (use_ws) {
        edge_csr_k<<<N_NODES_C / 4, 256, 0, stream>>>(
            pairs, rowst, P, W_edge_b, edge_out, 0);
    } else {
        edge_csr_k<<<N_NODES_C / 4, 256, 0, stream>>>(
            pairs, rowst, P, W_edge_b, edge_out, EDGE_HEAD_ROWS);
        edge_head_k<<<EDGE_HEAD_ROWS / 128, 256, 0, stream>>>(
            h_nodes, u, v, W_edge_w, W_edge_b, edge_out);
    }
}